// Round 8
// baseline (240.686 us; speedup 1.0000x reference)
//
#include <hip/hip_runtime.h>
#include <math.h>

#define DEV_INLINE __device__ __forceinline__

namespace {

typedef unsigned short u16;
typedef unsigned int u32;
typedef __attribute__((ext_vector_type(8))) short short8v;
typedef __attribute__((ext_vector_type(16))) float f32x16;

constexpr int Bn = 8, Cn = 32, Nn = 16384, Rn = 32, Vn = Rn * Rn * Rn;

DEV_INLINE float siluf(float x) { return x / (1.0f + __expf(-x)); }
DEV_INLINE float bf2f(u16 u) { union { u32 i; float f; } x; x.i = (u32)u << 16; return x.f; }
DEV_INLINE u16 f2bf(float f) {
  union { float f; u32 i; } x; x.f = f;
  return (u16)((x.i + 0x7FFFu + ((x.i >> 16) & 1u)) >> 16);
}
DEV_INLINE u32 pack2(float a, float b) { return (u32)f2bf(a) | ((u32)f2bf(b) << 16); }
DEV_INLINE void unpack8(uint4 u, float* f) {
  f[0] = bf2f(u.x & 0xffff); f[1] = bf2f(u.x >> 16);
  f[2] = bf2f(u.y & 0xffff); f[3] = bf2f(u.y >> 16);
  f[4] = bf2f(u.z & 0xffff); f[5] = bf2f(u.z >> 16);
  f[6] = bf2f(u.w & 0xffff); f[7] = bf2f(u.w >> 16);
}

// ---------------- coords stage 1: partial xyz sums ----------------
__global__ void k_cpart1(const float* __restrict__ coords, float* __restrict__ csum) {
  int blk = blockIdx.x;  // B*8
  int b = blk >> 3, s = blk & 7;
  int t = threadIdx.x;
  const float* cb = coords + (size_t)b * 3 * Nn;
  int n0 = s * 2048;
  float sx = 0.f, sy = 0.f, sz = 0.f;
  for (int n = n0 + t; n < n0 + 2048; n += 256) {
    sx += cb[n]; sy += cb[Nn + n]; sz += cb[2 * Nn + n];
  }
  #pragma unroll
  for (int m = 1; m <= 32; m <<= 1) {
    sx += __shfl_xor(sx, m); sy += __shfl_xor(sy, m); sz += __shfl_xor(sz, m);
  }
  __shared__ float rs[3][4];
  if ((t & 63) == 0) { rs[0][t >> 6] = sx; rs[1][t >> 6] = sy; rs[2][t >> 6] = sz; }
  __syncthreads();
  if (t < 3) atomicAdd(&csum[b * 4 + t], rs[t][0] + rs[t][1] + rs[t][2] + rs[t][3]);
}

// ---------------- coords stage 2: partial max of squared norm ----------------
__global__ void k_cpart2(const float* __restrict__ coords, const float* __restrict__ csum,
                         int* __restrict__ cmax) {
  int blk = blockIdx.x;  // B*8
  int b = blk >> 3, s = blk & 7;
  int t = threadIdx.x;
  const float* cb = coords + (size_t)b * 3 * Nn;
  const float invn = 1.0f / (float)Nn;
  float mx = csum[b * 4] * invn, my = csum[b * 4 + 1] * invn, mz = csum[b * 4 + 2] * invn;
  int n0 = s * 2048;
  float mq = 0.f;
  for (int n = n0 + t; n < n0 + 2048; n += 256) {
    float x = cb[n] - mx, y = cb[Nn + n] - my, z = cb[2 * Nn + n] - mz;
    mq = fmaxf(mq, x * x + y * y + z * z);
  }
  #pragma unroll
  for (int m = 1; m <= 32; m <<= 1) mq = fmaxf(mq, __shfl_xor(mq, m));
  __shared__ float rm[4];
  if ((t & 63) == 0) rm[t >> 6] = mq;
  __syncthreads();
  if (t == 0) {
    float v = fmaxf(fmaxf(rm[0], rm[1]), fmaxf(rm[2], rm[3]));
    atomicMax(cmax + b, __float_as_int(v));  // values >= 0 -> int-bits order ok
  }
}

// ---------------- coords stage 3: nc, voxel idx, histogram ----------------
__global__ void k_cfinal(const float* __restrict__ coords, const float* __restrict__ csum,
                         const int* __restrict__ cmax, float* __restrict__ nc,
                         int* __restrict__ vidx, int* __restrict__ hist) {
  int i = blockIdx.x * 256 + threadIdx.x;  // B*N
  int b = i >> 14, n = i & (Nn - 1);
  const float* cb = coords + (size_t)b * 3 * Nn;
  const float invn = 1.0f / (float)Nn;
  float mx = csum[b * 4] * invn, my = csum[b * 4 + 1] * invn, mz = csum[b * 4 + 2] * invn;
  float inv = 1.0f / (2.0f * sqrtf(__int_as_float(cmax[b])));
  float x = (cb[n] - mx) * inv + 0.5f;
  float y = (cb[Nn + n] - my) * inv + 0.5f;
  float z = (cb[2 * Nn + n] - mz) * inv + 0.5f;
  x = fminf(fmaxf(x * (float)Rn, 0.f), (float)(Rn - 1));
  y = fminf(fmaxf(y * (float)Rn, 0.f), (float)(Rn - 1));
  z = fminf(fmaxf(z * (float)Rn, 0.f), (float)(Rn - 1));
  float* ncb = nc + (size_t)b * 3 * Nn;
  ncb[n] = x; ncb[Nn + n] = y; ncb[2 * Nn + n] = z;
  int vx = (int)rintf(x), vy = (int)rintf(y), vz = (int)rintf(z);
  int v = (vx * Rn + vy) * Rn + vz;
  vidx[i] = v;
  atomicAdd(&hist[b * Vn + v], 1);
}

// ------- fused point branch: featT (f32 transpose) + px = feat@W.T+b (bf16 CL) -----
__global__ __launch_bounds__(256, 2) void k_pxlin(
    const float* __restrict__ feat, const float* __restrict__ w,
    const float* __restrict__ bias, float* __restrict__ featT,
    u16* __restrict__ pxb) {
  __shared__ float lw[1024];
  __shared__ float lb[32];
  __shared__ float lbuf[256 * 33];  // 33.8 KB transpose buffer (reused as u32)
  int t = threadIdx.x;
  for (int i = t; i < 1024; i += 256) lw[i] = w[i];
  if (t < 32) lb[t] = bias[t];
  int blk = blockIdx.x;  // B*64
  int b = blk >> 6, tile = blk & 63;
  int n0 = tile * 256, n = n0 + t;
  float fr[32];
  const float* fb = feat + (size_t)b * 32 * Nn + n;
  #pragma unroll
  for (int ci = 0; ci < 32; ++ci) {
    fr[ci] = fb[(size_t)ci * Nn];
    lbuf[t * 33 + ci] = fr[ci];
  }
  __syncthreads();
  float* ftb = featT + ((size_t)b * Nn + n0) * 32;
  #pragma unroll
  for (int j = 0; j < 32; ++j) {
    int idx = j * 256 + t;
    ftb[idx] = lbuf[(idx >> 5) * 33 + (idx & 31)];  // coalesced 1KB store
  }
  __syncthreads();
  u32* lbu = reinterpret_cast<u32*>(lbuf);
  #pragma unroll
  for (int p2 = 0; p2 < 16; ++p2) {
    int co0 = p2 * 2;
    float a0 = lb[co0], a1 = lb[co0 + 1];
    #pragma unroll
    for (int ci = 0; ci < 32; ++ci) {
      a0 += lw[co0 * 32 + ci] * fr[ci];
      a1 += lw[(co0 + 1) * 32 + ci] * fr[ci];
    }
    lbu[t * 17 + p2] = pack2(a0, a1);
  }
  __syncthreads();
  u32* pxu = reinterpret_cast<u32*>(pxb) + ((size_t)b * Nn + n0) * 16;
  #pragma unroll
  for (int j = 0; j < 16; ++j) {
    int idx = j * 256 + t;
    pxu[idx] = lbu[(idx >> 4) * 17 + (idx & 15)];
  }
}

// ---------------- scan stage 1: per-1024-chunk exclusive prefix ----------------
__global__ void k_scan1(const int* __restrict__ hist, int* __restrict__ offs,
                        int* __restrict__ bsum) {
  __shared__ int sd[256];
  int t = threadIdx.x, blk = blockIdx.x;  // 256 blocks
  int4 h = reinterpret_cast<const int4*>(hist)[blk * 256 + t];
  int s = h.x + h.y + h.z + h.w;
  sd[t] = s; __syncthreads();
  for (int off = 1; off < 256; off <<= 1) {
    int add = (t >= off) ? sd[t - off] : 0;
    __syncthreads();
    sd[t] += add;
    __syncthreads();
  }
  int excl = sd[t] - s;
  int4 o;
  o.x = excl; o.y = excl + h.x; o.z = o.y + h.y; o.w = o.z + h.z;
  reinterpret_cast<int4*>(offs)[blk * 256 + t] = o;
  if (t == 0) bsum[blk] = sd[255];
}

// ---------------- scan stage 2: exclusive scan of 256 block sums ----------------
__global__ void k_scan2(const int* __restrict__ bsum, int* __restrict__ bbase) {
  __shared__ int sd[256];
  int t = threadIdx.x;
  int s = bsum[t];
  sd[t] = s; __syncthreads();
  for (int off = 1; off < 256; off <<= 1) {
    int add = (t >= off) ? sd[t - off] : 0;
    __syncthreads();
    sd[t] += add;
    __syncthreads();
  }
  bbase[t] = sd[t] - s;
}

// ---------------- cursor-scatter point indices into sorted order ----------------
__global__ void k_sortidx(const int* __restrict__ vidx, int* __restrict__ offs,
                          const int* __restrict__ bbase, int* __restrict__ pidx) {
  int i = blockIdx.x * 256 + threadIdx.x;  // B*N
  int b = i >> 14, n = i & (Nn - 1);
  int g = b * Vn + vidx[i];
  int p = atomicAdd(&offs[g], 1) + bbase[g >> 10];
  pidx[p] = n;
}

// ---------------- per-voxel average -> bf16 channel-last vox0 ----------------
__global__ void k_voxavg(const int* __restrict__ hist, const int* __restrict__ offs,
                         const int* __restrict__ bbase, const int* __restrict__ pidx,
                         const float* __restrict__ featT, uint2* __restrict__ vox0) {
  int t = threadIdx.x;
  int wv = blockIdx.x * 4 + (t >> 6);  // global voxel id, B*V total
  int lane = t & 63;
  int c4 = lane & 7, j = lane >> 3;
  int b = wv >> 15;
  int cnt = hist[wv];
  float ax = 0.f, ay = 0.f, az = 0.f, aw = 0.f;
  if (cnt > 0) {
    int end = offs[wv] + bbase[wv >> 10];  // offs is post-scatter cursor = local end
    int start = end - cnt;
    const float4* ft = reinterpret_cast<const float4*>(featT) + (size_t)b * Nn * 8;
    for (int k = start + j; k < end; k += 8) {
      int n = pidx[k];
      float4 v = ft[n * 8 + c4];
      ax += v.x; ay += v.y; az += v.z; aw += v.w;
    }
    #pragma unroll
    for (int m = 8; m <= 32; m <<= 1) {
      ax += __shfl_xor(ax, m); ay += __shfl_xor(ay, m);
      az += __shfl_xor(az, m); aw += __shfl_xor(aw, m);
    }
    float invc = 1.0f / (float)cnt;
    ax *= invc; ay *= invc; az *= invc; aw *= invc;
  }
  if (j == 0) {
    uint2 o;
    o.x = pack2(ax, ay);
    o.y = pack2(az, aw);
    vox0[(size_t)wv * 8 + c4] = o;
  }
}

// -------- weight permute for 32x32x16 A-frag: w[co][ci][k] -> wt[k][h][lane][e] ----
__global__ void k_twz(const float* __restrict__ w, u16* __restrict__ wt) {
  int i = blockIdx.x * 256 + threadIdx.x;
  if (i >= 27 * 32 * 32) return;
  int e = i & 7, l = (i >> 3) & 63, h = (i >> 9) & 1, k = i >> 10;
  int co = l & 31, ci = h * 16 + ((l >> 5) << 3) + e;
  wt[i] = f2bf(w[(co * 32 + ci) * 27 + k]);
}

// ------- modulation vectors m = silu(cond) @ mw.T + mb (wave-per-row, coalesced) ----
__global__ void k_mods(const float* __restrict__ cond,
                       const float* __restrict__ w1, const float* __restrict__ b1,
                       const float* __restrict__ w2, const float* __restrict__ b2,
                       const float* __restrict__ wp, const float* __restrict__ bp,
                       float* __restrict__ m1, float* __restrict__ m2,
                       float* __restrict__ mp) {
  int blk = blockIdx.x;  // 24 = mat*8 + b
  int mat = blk >> 3, b = blk & 7;
  int t = threadIdx.x;  // 256
  __shared__ float sc[256];
  sc[t] = siluf(cond[b * 256 + t]);
  __syncthreads();
  const float* w = (mat == 0) ? w1 : ((mat == 1) ? w2 : wp);
  const float* bb = (mat == 0) ? b1 : ((mat == 1) ? b2 : bp);
  float* dst = (mat == 0) ? m1 : ((mat == 1) ? m2 : mp);
  int wave = t >> 6, lane = t & 63;
  const float4* w4 = reinterpret_cast<const float4*>(w);
  float4 sv = reinterpret_cast<const float4*>(sc)[lane];
  #pragma unroll
  for (int i = 0; i < 16; ++i) {
    int oo = wave * 16 + i;
    float4 wv = w4[oo * 64 + lane];
    float p = wv.x * sv.x + wv.y * sv.y + wv.z * sv.z + wv.w * sv.w;
    #pragma unroll
    for (int m = 1; m <= 32; m <<= 1) p += __shfl_xor(p, m);
    if (lane == 0) dst[b * 64 + oo] = p + bb[oo];
  }
}

// ------- 3x3x3 conv, bf16 MFMA 32x32x16, fused per-block GN partial stats ---------
__global__ __launch_bounds__(512, 2) void k_conv(
    const u16* __restrict__ in, const u16* __restrict__ wt,
    const float* __restrict__ bias, u16* __restrict__ out,
    float* __restrict__ pstat) {
  __shared__ uint4 lds_w4[3456];   // 55296 B
  __shared__ uint4 lds_x4[4096];   // 65536 B (4080 used)
  int t = threadIdx.x;
  int blk = blockIdx.x;
  int yp = blk & 3, x = (blk >> 2) & 31, b = blk >> 7;
  int y0 = yp * 8;
  size_t bbase = (size_t)b * Vn;

  const uint4* gw = reinterpret_cast<const uint4*>(wt);
  for (int i = t; i < 3456; i += 512) lds_w4[i] = gw[i];

  for (int i = t; i < 4080; i += 512) {
    int col = i / 136, rem = i - col * 136;
    int c4 = rem / 34, r = rem - c4 * 34;
    int dxp = col / 10, yy = col - dxp * 10;
    int gx = x + dxp - 1, gy = y0 + yy - 1, z = r - 1;
    uint4 val = make_uint4(0u, 0u, 0u, 0u);
    if (gx >= 0 && gx < 32 && (unsigned)gy < 32u && (unsigned)z < 32u) {
      val = *reinterpret_cast<const uint4*>(
          in + (bbase + (size_t)((gx * 32 + gy) * 32 + z)) * 32 + c4 * 8);
    }
    lds_x4[i] = val;
  }
  __syncthreads();

  int w = t >> 6, lane = t & 63;
  int zc = lane & 31, hi = lane >> 5;
  int y = y0 + w;

  f32x16 acc;
  #pragma unroll
  for (int q = 0; q < 4; ++q) {
    float4 bq = *reinterpret_cast<const float4*>(bias + q * 8 + hi * 4);
    acc[q * 4 + 0] = bq.x; acc[q * 4 + 1] = bq.y;
    acc[q * 4 + 2] = bq.z; acc[q * 4 + 3] = bq.w;
  }

  const u16* lw = reinterpret_cast<const u16*>(lds_w4);
  const u16* lx = reinterpret_cast<const u16*>(lds_x4);

  #pragma unroll
  for (int dxp = 0; dxp < 3; ++dxp) {
    #pragma unroll
    for (int dyp = 0; dyp < 3; ++dyp) {
      int col = dxp * 10 + w + dyp;
      #pragma unroll
      for (int dzp = 0; dzp < 3; ++dzp) {
        int k = (dxp * 3 + dyp) * 3 + dzp;
        short8v a0 = *reinterpret_cast<const short8v*>(lw + ((k * 2 + 0) * 64 + lane) * 8);
        short8v a1 = *reinterpret_cast<const short8v*>(lw + ((k * 2 + 1) * 64 + lane) * 8);
        short8v b0 = *reinterpret_cast<const short8v*>(
            lx + ((col * 4 + hi) * 34 + zc + dzp) * 8);
        short8v b1 = *reinterpret_cast<const short8v*>(
            lx + ((col * 4 + 2 + hi) * 34 + zc + dzp) * 8);
        acc = __builtin_amdgcn_mfma_f32_32x32x16_bf16(a0, b0, acc, 0, 0, 0);
        acc = __builtin_amdgcn_mfma_f32_32x32x16_bf16(a1, b1, acc, 0, 0, 0);
      }
    }
  }

  // C/D: col(z)=lane&31, row(co)=(reg&3)+8*(reg>>2)+4*(lane>>5)
  size_t off = (bbase + (size_t)((x * 32 + y) * 32 + zc)) * 32;
  #pragma unroll
  for (int q = 0; q < 4; ++q) {
    uint2 o;
    o.x = pack2(acc[q * 4 + 0], acc[q * 4 + 1]);
    o.y = pack2(acc[q * 4 + 2], acc[q * 4 + 3]);
    *reinterpret_cast<uint2*>(out + off + q * 8 + hi * 4) = o;
  }

  // ---- per-block per-channel partial sum/sumsq (no atomics) ----
  float s16[16], q16[16];
  #pragma unroll
  for (int r = 0; r < 16; ++r) { s16[r] = acc[r]; q16[r] = acc[r] * acc[r]; }
  #pragma unroll
  for (int m = 1; m <= 16; m <<= 1) {
    #pragma unroll
    for (int r = 0; r < 16; ++r) {
      s16[r] += __shfl_xor(s16[r], m);
      q16[r] += __shfl_xor(q16[r], m);
    }
  }
  __syncthreads();  // all waves done reading lds_w4 -> reuse as reduce buffer
  float* sred = reinterpret_cast<float*>(lds_w4);
  if ((lane & 31) == 0) {
    #pragma unroll
    for (int r = 0; r < 16; ++r) {
      int co = (r & 3) + 8 * (r >> 2) + 4 * hi;
      sred[w * 64 + co] = s16[r];
      sred[512 + w * 64 + co] = q16[r];
    }
  }
  __syncthreads();
  if (t < 64) {
    int arr = t >> 5, c = t & 31;
    const float* bp_ = sred + arr * 512 + c;
    float v = bp_[0] + bp_[64] + bp_[128] + bp_[192] +
              bp_[256] + bp_[320] + bp_[384] + bp_[448];
    pstat[blk * 64 + arr * 32 + c] = v;
  }
}

// ---------------- elementwise affine+silu on vox (in place) ----------------
__global__ void k_affsilu(uint4* __restrict__ x, const float* __restrict__ Ac,
                          const float* __restrict__ Bc) {
  int i = blockIdx.x * 256 + threadIdx.x;  // B*V*4 uint4s
  int c4 = i & 3, b = i >> 17;
  uint4 v = x[i];
  float f[8];
  unpack8(v, f);
  float4 A0 = reinterpret_cast<const float4*>(Ac)[b * 8 + c4 * 2];
  float4 A1 = reinterpret_cast<const float4*>(Ac)[b * 8 + c4 * 2 + 1];
  float4 B0 = reinterpret_cast<const float4*>(Bc)[b * 8 + c4 * 2];
  float4 B1 = reinterpret_cast<const float4*>(Bc)[b * 8 + c4 * 2 + 1];
  f[0] = siluf(f[0] * A0.x + B0.x); f[1] = siluf(f[1] * A0.y + B0.y);
  f[2] = siluf(f[2] * A0.z + B0.z); f[3] = siluf(f[3] * A0.w + B0.w);
  f[4] = siluf(f[4] * A1.x + B1.x); f[5] = siluf(f[5] * A1.y + B1.y);
  f[6] = siluf(f[6] * A1.z + B1.z); f[7] = siluf(f[7] * A1.w + B1.w);
  uint4 o;
  o.x = pack2(f[0], f[1]); o.y = pack2(f[2], f[3]);
  o.z = pack2(f[4], f[5]); o.w = pack2(f[6], f[7]);
  x[i] = o;
}

// ------- per-channel sum/sumsq on channel-last bf16, linear chunks (for pxb) -------
__global__ void k_statspx(const u16* __restrict__ x, float* __restrict__ psum,
                          float* __restrict__ psq, int segs) {
  int blk = blockIdx.x;  // B*segs chunks of 4096 uint4
  int b = blk / segs;
  int t = threadIdx.x;
  int c8 = t & 3, vsub = t >> 2;
  float s[8], q[8];
  #pragma unroll
  for (int j = 0; j < 8; ++j) { s[j] = 0.f; q[j] = 0.f; }
  const uint4* xb = reinterpret_cast<const uint4*>(x) + (size_t)blk * 4096;
  for (int it = 0; it < 16; ++it) {
    int v = it * 64 + vsub;
    uint4 u = xb[v * 4 + c8];
    float f[8];
    unpack8(u, f);
    #pragma unroll
    for (int j = 0; j < 8; ++j) { s[j] += f[j]; q[j] += f[j] * f[j]; }
  }
  #pragma unroll
  for (int m = 4; m <= 32; m <<= 1) {
    #pragma unroll
    for (int j = 0; j < 8; ++j) {
      s[j] += __shfl_xor(s[j], m);
      q[j] += __shfl_xor(q[j], m);
    }
  }
  __shared__ float ls[2][4][4][8];
  int wv = t >> 6;
  if ((t & 63) < 4) {
    #pragma unroll
    for (int j = 0; j < 8; ++j) { ls[0][wv][c8][j] = s[j]; ls[1][wv][c8][j] = q[j]; }
  }
  __syncthreads();
  if (t < 64) {
    int arr = t >> 5, c = t & 31;
    float v = ls[arr][0][c >> 3][c & 7] + ls[arr][1][c >> 3][c & 7] +
              ls[arr][2][c >> 3][c & 7] + ls[arr][3][c >> 3][c & 7];
    atomicAdd((arr == 0 ? psum : psq) + b * 32 + c, v);
  }
}

// ------- AdaGN affine coefs (stage 1) from conv per-block partials ----------------
__global__ void k_coef1(const float* __restrict__ pstat, const float* __restrict__ mod,
                        const float* __restrict__ g, const float* __restrict__ bgn,
                        float* __restrict__ A, float* __restrict__ Bc) {
  int t = threadIdx.x;  // 256 = B*C
  int b = t >> 5, c = t & 31;
  float cs = 0.f, cq = 0.f;
  const float* p = pstat + (size_t)b * 128 * 64;
  for (int i = 0; i < 128; ++i) {
    cs += p[i * 64 + c];
    cq += p[i * 64 + 32 + c];
  }
  __shared__ float ls[256], lq[256];
  ls[t] = cs; lq[t] = cq;
  __syncthreads();
  int gb = t & ~3;
  float s4 = ls[gb] + ls[gb + 1] + ls[gb + 2] + ls[gb + 3];
  float q4 = lq[gb] + lq[gb + 1] + lq[gb + 2] + lq[gb + 3];
  const float cntf = 4.0f * (float)Vn;
  float mean = s4 / cntf;
  float var = q4 / cntf - mean * mean;
  float rstd = rsqrtf(var + 1e-5f);
  float scale = mod[b * 64 + c], shift = mod[b * 64 + 32 + c];
  A[t] = rstd * g[c] * scale;
  Bc[t] = (bgn[c] - mean * rstd * g[c]) * scale + shift;
}

// ------- AdaGN stage 2 + SE from conv partials -> gather affine S,T ---------------
__global__ void k_coef2(const float* __restrict__ pstat, const float* __restrict__ mod,
                        const float* __restrict__ g, const float* __restrict__ bgn,
                        const float* __restrict__ sw1, const float* __restrict__ sw2,
                        float* __restrict__ S, float* __restrict__ T) {
  __shared__ float zm[8][32];
  __shared__ float hh[8][4];
  __shared__ float ls[256], lq[256];
  int t = threadIdx.x;  // 256 = B*C
  int b = t >> 5, c = t & 31;
  float cs = 0.f, cq = 0.f;
  const float* p = pstat + (size_t)b * 128 * 64;
  for (int i = 0; i < 128; ++i) {
    cs += p[i * 64 + c];
    cq += p[i * 64 + 32 + c];
  }
  ls[t] = cs; lq[t] = cq;
  __syncthreads();
  int gb = t & ~3;
  float s4 = ls[gb] + ls[gb + 1] + ls[gb + 2] + ls[gb + 3];
  float q4 = lq[gb] + lq[gb + 1] + lq[gb + 2] + lq[gb + 3];
  const float cntf = 4.0f * (float)Vn;
  float mean = s4 / cntf;
  float var = q4 / cntf - mean * mean;
  float rstd = rsqrtf(var + 1e-5f);
  float scale = mod[b * 64 + c], shift = mod[b * 64 + 32 + c];
  float A = rstd * g[c] * scale;
  float Bv = (bgn[c] - mean * rstd * g[c]) * scale + shift;
  float chmean = cs / (float)Vn;
  zm[b][c] = A * chmean + Bv;
  __syncthreads();
  if (t < 32) {
    int b2 = t >> 2, j = t & 3;
    float h = 0;
    for (int cc = 0; cc < 32; ++cc) h += sw1[j * 32 + cc] * zm[b2][cc];
    hh[b2][j] = fmaxf(h, 0.f);
  }
  __syncthreads();
  float sig = 0;
  for (int j = 0; j < 4; ++j) sig += sw2[c * 4 + j] * hh[b][j];
  sig = 1.0f / (1.0f + __expf(-sig));
  S[t] = A * sig;
  T[t] = Bv * sig;
}

// ---------------- point-branch affine coefficients ----------------
__global__ void k_coefp(const float* __restrict__ psum, const float* __restrict__ psq,
                        const float* __restrict__ mod, const float* __restrict__ g,
                        const float* __restrict__ bgn, float* __restrict__ A,
                        float* __restrict__ Bc) {
  __shared__ float ls[256], lq[256];
  int t = threadIdx.x;  // 256 = B*C
  int b = t >> 5, c = t & 31;
  ls[t] = psum[t]; lq[t] = psq[t];
  __syncthreads();
  int gb = t & ~3;
  float s4 = ls[gb] + ls[gb + 1] + ls[gb + 2] + ls[gb + 3];
  float q4 = lq[gb] + lq[gb + 1] + lq[gb + 2] + lq[gb + 3];
  const float cntf = 4.0f * (float)Nn;
  float m = s4 / cntf;
  float var = q4 / cntf - m * m;
  float r = rsqrtf(var + 1e-5f);
  float scale = mod[b * 64 + c], shift = mod[b * 64 + 32 + c];
  A[t] = r * g[c] * scale;
  Bc[t] = (bgn[c] - m * r * g[c]) * scale + shift;
}

// ------- fused: trilinear devox (affine S,T) + silu(px*Ap+Bp) point branch --------
__global__ void k_devoxfinal(const u16* __restrict__ vox, const float* __restrict__ nc,
                             const u16* __restrict__ pxb, const float* __restrict__ S,
                             const float* __restrict__ T, const float* __restrict__ Ap,
                             const float* __restrict__ Bp, float* __restrict__ out) {
  int i = blockIdx.x * 256 + threadIdx.x;  // B*N
  int b = i >> 14, n = i & (Nn - 1);
  const float* ncb = nc + (size_t)b * 3 * Nn;
  float fx = ncb[n], fy = ncb[Nn + n], fz = ncb[2 * Nn + n];
  float lxf = floorf(fx), lyf = floorf(fy), lzf = floorf(fz);
  float wx1 = fx - lxf, wy1 = fy - lyf, wz1 = fz - lzf;
  int lx = (int)lxf, ly = (int)lyf, lz = (int)lzf;
  int hx = min(lx + 1, 31), hy = min(ly + 1, 31), hz = min(lz + 1, 31);
  float a[32];
  #pragma unroll
  for (int c = 0; c < 32; ++c) a[c] = 0.f;
  for (int corner = 0; corner < 8; ++corner) {
    int cx = (corner & 4) ? hx : lx;
    int cy = (corner & 2) ? hy : ly;
    int cz = (corner & 1) ? hz : lz;
    float ww = ((corner & 4) ? wx1 : 1.f - wx1) *
               ((corner & 2) ? wy1 : 1.f - wy1) *
               ((corner & 1) ? wz1 : 1.f - wz1);
    const uint4* p = reinterpret_cast<const uint4*>(
        vox + ((size_t)b * Vn + (size_t)((cx * 32 + cy) * 32 + cz)) * 32);
    #pragma unroll
    for (int qq = 0; qq < 4; ++qq) {
      float f[8];
      unpack8(p[qq], f);
      #pragma unroll
      for (int j = 0; j < 8; ++j) a[qq * 8 + j] += ww * f[j];
    }
  }
  const uint4* pp = reinterpret_cast<const uint4*>(pxb) + (size_t)i * 4;
  float* o = out + (size_t)b * 32 * Nn + n;
  #pragma unroll
  for (int qq = 0; qq < 4; ++qq) {
    float pf[8];
    unpack8(pp[qq], pf);
    #pragma unroll
    for (int j = 0; j < 8; ++j) {
      int c = qq * 8 + j;
      float y = pf[j] * Ap[b * 32 + c] + Bp[b * 32 + c];
      o[(size_t)c * Nn] = a[c] * S[b * 32 + c] + T[b * 32 + c] + siluf(y);
    }
  }
}

}  // namespace

extern "C" void kernel_launch(void* const* d_in, const int* in_sizes, int n_in,
                              void* d_out, int out_size, void* d_ws, size_t ws_size,
                              hipStream_t stream) {
  (void)in_sizes; (void)n_in; (void)out_size; (void)ws_size;
  const float* features = (const float*)d_in[0];
  const float* coords = (const float*)d_in[1];
  const float* condition = (const float*)d_in[2];
  const float* conv1_w = (const float*)d_in[3];
  const float* conv1_b = (const float*)d_in[4];
  const float* gn1_g = (const float*)d_in[5];
  const float* gn1_b = (const float*)d_in[6];
  const float* mod1_w = (const float*)d_in[7];
  const float* mod1_b = (const float*)d_in[8];
  const float* conv2_w = (const float*)d_in[9];
  const float* conv2_b = (const float*)d_in[10];
  const float* gn2_g = (const float*)d_in[11];
  const float* gn2_b = (const float*)d_in[12];
  const float* mod2_w = (const float*)d_in[13];
  const float* mod2_b = (const float*)d_in[14];
  const float* se_w1 = (const float*)d_in[15];
  const float* se_w2 = (const float*)d_in[16];
  const float* pc_w = (const float*)d_in[17];
  const float* pc_b = (const float*)d_in[18];
  const float* gnp_g = (const float*)d_in[19];
  const float* gnp_b = (const float*)d_in[20];
  const float* modp_w = (const float*)d_in[21];
  const float* modp_b = (const float*)d_in[22];

  char* w = (char*)d_ws;
  // R0a (16.8 MB): featT f32 (pxlin -> voxavg), then vox1 bf16 (conv1 -> affsilu -> conv2)
  float* featT = (float*)w;
  u16* vox1 = (u16*)w;
  w += 16777216;
  u16* vox2 = (u16*)w; w += 16777216;   // conv2 out -> devoxfinal
  u16* vox0 = (u16*)w; w += 16777216;   // voxavg -> conv1
  u16* pxb = (u16*)w;  w += 8388608;    // point-branch bf16 CL (pxlin -> devoxfinal)
  int* hist = (int*)w;  w += 1048576;   // memset block: hist, psump, psqp, csum, cmax
  float* psump = (float*)w; w += 1024;
  float* psqp = (float*)w;  w += 1024;
  float* csum = (float*)w;  w += 128;
  int* cmax = (int*)w;      w += 64;
  int* offs = (int*)w;  w += 1048576;
  int* bsum = (int*)w;  w += 1024;
  int* bbase = (int*)w; w += 1024;
  int* pidx = (int*)w;  w += 524288;
  float* ncb = (float*)w;   w += 1572864;
  int* vidx = (int*)w;      w += 524288;
  u16* wt1b = (u16*)w;      w += 55296;
  u16* wt2b = (u16*)w;      w += 55296;
  float* pstat1 = (float*)w; w += 262144;
  float* pstat2 = (float*)w; w += 262144;
  float* m1 = (float*)w;    w += 2048;
  float* m2 = (float*)w;    w += 2048;
  float* mp = (float*)w;    w += 2048;
  float* A1 = (float*)w;    w += 1024;
  float* B1 = (float*)w;    w += 1024;
  float* Sc = (float*)w;    w += 1024;
  float* Tc = (float*)w;    w += 1024;
  float* Ap = (float*)w;    w += 1024;
  float* Bp = (float*)w;    w += 1024;
  float* out = (float*)d_out;

  hipMemsetAsync(hist, 0, 1048576 + 1024 + 1024 + 128 + 64, stream);

  k_pxlin<<<Bn * 64, 256, 0, stream>>>(features, pc_w, pc_b, featT, pxb);
  k_cpart1<<<Bn * 8, 256, 0, stream>>>(coords, csum);
  k_twz<<<108, 256, 0, stream>>>(conv1_w, wt1b);
  k_twz<<<108, 256, 0, stream>>>(conv2_w, wt2b);
  k_mods<<<24, 256, 0, stream>>>(condition, mod1_w, mod1_b, mod2_w, mod2_b,
                                 modp_w, modp_b, m1, m2, mp);
  k_statspx<<<Bn * 16, 256, 0, stream>>>(pxb, psump, psqp, 16);
  k_coefp<<<1, 256, 0, stream>>>(psump, psqp, mp, gnp_g, gnp_b, Ap, Bp);
  k_cpart2<<<Bn * 8, 256, 0, stream>>>(coords, csum, cmax);
  k_cfinal<<<(Bn * Nn) / 256, 256, 0, stream>>>(coords, csum, cmax, ncb, vidx, hist);
  k_scan1<<<256, 256, 0, stream>>>(hist, offs, bsum);
  k_scan2<<<1, 256, 0, stream>>>(bsum, bbase);
  k_sortidx<<<(Bn * Nn) / 256, 256, 0, stream>>>(vidx, offs, bbase, pidx);
  k_voxavg<<<(Bn * Vn) / 4, 256, 0, stream>>>(hist, offs, bbase, pidx, featT,
                                              (uint2*)vox0);
  k_conv<<<1024, 512, 0, stream>>>(vox0, wt1b, conv1_b, vox1, pstat1);
  k_coef1<<<1, 256, 0, stream>>>(pstat1, m1, gn1_g, gn1_b, A1, B1);
  k_affsilu<<<4096, 256, 0, stream>>>((uint4*)vox1, A1, B1);
  k_conv<<<1024, 512, 0, stream>>>(vox1, wt2b, conv2_b, vox2, pstat2);
  k_coef2<<<1, 256, 0, stream>>>(pstat2, m2, gn2_g, gn2_b, se_w1, se_w2, Sc, Tc);
  k_devoxfinal<<<(Bn * Nn) / 256, 256, 0, stream>>>(vox2, ncb, pxb, Sc, Tc, Ap, Bp, out);
}

// Round 9
// 222.116 us; speedup vs baseline: 1.0836x; 1.0836x over previous
//
#include <hip/hip_runtime.h>
#include <math.h>

#define DEV_INLINE __device__ __forceinline__

namespace {

typedef unsigned short u16;
typedef unsigned int u32;
typedef __attribute__((ext_vector_type(8))) short short8v;
typedef __attribute__((ext_vector_type(16))) float f32x16;

constexpr int Bn = 8, Cn = 32, Nn = 16384, Rn = 32, Vn = Rn * Rn * Rn;

DEV_INLINE float siluf(float x) { return x / (1.0f + __expf(-x)); }
DEV_INLINE float bf2f(u16 u) { union { u32 i; float f; } x; x.i = (u32)u << 16; return x.f; }
DEV_INLINE u16 f2bf(float f) {
  union { float f; u32 i; } x; x.f = f;
  return (u16)((x.i + 0x7FFFu + ((x.i >> 16) & 1u)) >> 16);
}
DEV_INLINE u32 pack2(float a, float b) { return (u32)f2bf(a) | ((u32)f2bf(b) << 16); }
DEV_INLINE void unpack8(uint4 u, float* f) {
  f[0] = bf2f(u.x & 0xffff); f[1] = bf2f(u.x >> 16);
  f[2] = bf2f(u.y & 0xffff); f[3] = bf2f(u.y >> 16);
  f[4] = bf2f(u.z & 0xffff); f[5] = bf2f(u.z >> 16);
  f[6] = bf2f(u.w & 0xffff); f[7] = bf2f(u.w >> 16);
}

// ---------------- coords stage 1: partial xyz sums ----------------
__global__ void k_cpart1(const float* __restrict__ coords, float* __restrict__ csum) {
  int blk = blockIdx.x;  // B*8
  int b = blk >> 3, s = blk & 7;
  int t = threadIdx.x;
  const float* cb = coords + (size_t)b * 3 * Nn;
  int n0 = s * 2048;
  float sx = 0.f, sy = 0.f, sz = 0.f;
  for (int n = n0 + t; n < n0 + 2048; n += 256) {
    sx += cb[n]; sy += cb[Nn + n]; sz += cb[2 * Nn + n];
  }
  #pragma unroll
  for (int m = 1; m <= 32; m <<= 1) {
    sx += __shfl_xor(sx, m); sy += __shfl_xor(sy, m); sz += __shfl_xor(sz, m);
  }
  __shared__ float rs[3][4];
  if ((t & 63) == 0) { rs[0][t >> 6] = sx; rs[1][t >> 6] = sy; rs[2][t >> 6] = sz; }
  __syncthreads();
  if (t < 3) atomicAdd(&csum[b * 4 + t], rs[t][0] + rs[t][1] + rs[t][2] + rs[t][3]);
}

// ---------------- coords stage 2: partial max of squared norm ----------------
__global__ void k_cpart2(const float* __restrict__ coords, const float* __restrict__ csum,
                         int* __restrict__ cmax) {
  int blk = blockIdx.x;  // B*8
  int b = blk >> 3, s = blk & 7;
  int t = threadIdx.x;
  const float* cb = coords + (size_t)b * 3 * Nn;
  const float invn = 1.0f / (float)Nn;
  float mx = csum[b * 4] * invn, my = csum[b * 4 + 1] * invn, mz = csum[b * 4 + 2] * invn;
  int n0 = s * 2048;
  float mq = 0.f;
  for (int n = n0 + t; n < n0 + 2048; n += 256) {
    float x = cb[n] - mx, y = cb[Nn + n] - my, z = cb[2 * Nn + n] - mz;
    mq = fmaxf(mq, x * x + y * y + z * z);
  }
  #pragma unroll
  for (int m = 1; m <= 32; m <<= 1) mq = fmaxf(mq, __shfl_xor(mq, m));
  __shared__ float rm[4];
  if ((t & 63) == 0) rm[t >> 6] = mq;
  __syncthreads();
  if (t == 0) {
    float v = fmaxf(fmaxf(rm[0], rm[1]), fmaxf(rm[2], rm[3]));
    atomicMax(cmax + b, __float_as_int(v));  // values >= 0 -> int-bits order ok
  }
}

// ---------------- coords stage 3: nc, voxel idx, histogram ----------------
__global__ void k_cfinal(const float* __restrict__ coords, const float* __restrict__ csum,
                         const int* __restrict__ cmax, float* __restrict__ nc,
                         int* __restrict__ vidx, int* __restrict__ hist) {
  int i = blockIdx.x * 256 + threadIdx.x;  // B*N
  int b = i >> 14, n = i & (Nn - 1);
  const float* cb = coords + (size_t)b * 3 * Nn;
  const float invn = 1.0f / (float)Nn;
  float mx = csum[b * 4] * invn, my = csum[b * 4 + 1] * invn, mz = csum[b * 4 + 2] * invn;
  float inv = 1.0f / (2.0f * sqrtf(__int_as_float(cmax[b])));
  float x = (cb[n] - mx) * inv + 0.5f;
  float y = (cb[Nn + n] - my) * inv + 0.5f;
  float z = (cb[2 * Nn + n] - mz) * inv + 0.5f;
  x = fminf(fmaxf(x * (float)Rn, 0.f), (float)(Rn - 1));
  y = fminf(fmaxf(y * (float)Rn, 0.f), (float)(Rn - 1));
  z = fminf(fmaxf(z * (float)Rn, 0.f), (float)(Rn - 1));
  float* ncb = nc + (size_t)b * 3 * Nn;
  ncb[n] = x; ncb[Nn + n] = y; ncb[2 * Nn + n] = z;
  int vx = (int)rintf(x), vy = (int)rintf(y), vz = (int)rintf(z);
  int v = (vx * Rn + vy) * Rn + vz;
  vidx[i] = v;
  atomicAdd(&hist[b * Vn + v], 1);
}

// ------- fused point branch: featT (f32 transpose) + px = feat@W.T+b (bf16 CL) -----
__global__ __launch_bounds__(256, 2) void k_pxlin(
    const float* __restrict__ feat, const float* __restrict__ w,
    const float* __restrict__ bias, float* __restrict__ featT,
    u16* __restrict__ pxb) {
  __shared__ float lw[1024];
  __shared__ float lb[32];
  __shared__ float lbuf[256 * 33];  // 33.8 KB transpose buffer (reused as u32)
  int t = threadIdx.x;
  for (int i = t; i < 1024; i += 256) lw[i] = w[i];
  if (t < 32) lb[t] = bias[t];
  int blk = blockIdx.x;  // B*64
  int b = blk >> 6, tile = blk & 63;
  int n0 = tile * 256, n = n0 + t;
  float fr[32];
  const float* fb = feat + (size_t)b * 32 * Nn + n;
  #pragma unroll
  for (int ci = 0; ci < 32; ++ci) {
    fr[ci] = fb[(size_t)ci * Nn];
    lbuf[t * 33 + ci] = fr[ci];
  }
  __syncthreads();
  float* ftb = featT + ((size_t)b * Nn + n0) * 32;
  #pragma unroll
  for (int j = 0; j < 32; ++j) {
    int idx = j * 256 + t;
    ftb[idx] = lbuf[(idx >> 5) * 33 + (idx & 31)];  // coalesced 1KB store
  }
  __syncthreads();
  u32* lbu = reinterpret_cast<u32*>(lbuf);
  #pragma unroll
  for (int p2 = 0; p2 < 16; ++p2) {
    int co0 = p2 * 2;
    float a0 = lb[co0], a1 = lb[co0 + 1];
    #pragma unroll
    for (int ci = 0; ci < 32; ++ci) {
      a0 += lw[co0 * 32 + ci] * fr[ci];
      a1 += lw[(co0 + 1) * 32 + ci] * fr[ci];
    }
    lbu[t * 17 + p2] = pack2(a0, a1);
  }
  __syncthreads();
  u32* pxu = reinterpret_cast<u32*>(pxb) + ((size_t)b * Nn + n0) * 16;
  #pragma unroll
  for (int j = 0; j < 16; ++j) {
    int idx = j * 256 + t;
    pxu[idx] = lbu[(idx >> 4) * 17 + (idx & 15)];
  }
}

// ---------------- scan stage 1: per-1024-chunk exclusive prefix ----------------
__global__ void k_scan1(const int* __restrict__ hist, int* __restrict__ offs,
                        int* __restrict__ bsum) {
  __shared__ int sd[256];
  int t = threadIdx.x, blk = blockIdx.x;  // 256 blocks
  int4 h = reinterpret_cast<const int4*>(hist)[blk * 256 + t];
  int s = h.x + h.y + h.z + h.w;
  sd[t] = s; __syncthreads();
  for (int off = 1; off < 256; off <<= 1) {
    int add = (t >= off) ? sd[t - off] : 0;
    __syncthreads();
    sd[t] += add;
    __syncthreads();
  }
  int excl = sd[t] - s;
  int4 o;
  o.x = excl; o.y = excl + h.x; o.z = o.y + h.y; o.w = o.z + h.z;
  reinterpret_cast<int4*>(offs)[blk * 256 + t] = o;
  if (t == 0) bsum[blk] = sd[255];
}

// ---------------- scan stage 2: exclusive scan of 256 block sums ----------------
__global__ void k_scan2(const int* __restrict__ bsum, int* __restrict__ bbase) {
  __shared__ int sd[256];
  int t = threadIdx.x;
  int s = bsum[t];
  sd[t] = s; __syncthreads();
  for (int off = 1; off < 256; off <<= 1) {
    int add = (t >= off) ? sd[t - off] : 0;
    __syncthreads();
    sd[t] += add;
    __syncthreads();
  }
  bbase[t] = sd[t] - s;
}

// ---------------- cursor-scatter point indices into sorted order ----------------
__global__ void k_sortidx(const int* __restrict__ vidx, int* __restrict__ offs,
                          const int* __restrict__ bbase, int* __restrict__ pidx) {
  int i = blockIdx.x * 256 + threadIdx.x;  // B*N
  int b = i >> 14, n = i & (Nn - 1);
  int g = b * Vn + vidx[i];
  int p = atomicAdd(&offs[g], 1) + bbase[g >> 10];
  pidx[p] = n;
}

// ---------------- per-voxel average -> bf16 channel-last vox0 ----------------
__global__ void k_voxavg(const int* __restrict__ hist, const int* __restrict__ offs,
                         const int* __restrict__ bbase, const int* __restrict__ pidx,
                         const float* __restrict__ featT, uint2* __restrict__ vox0) {
  int t = threadIdx.x;
  int wv = blockIdx.x * 4 + (t >> 6);  // global voxel id, B*V total
  int lane = t & 63;
  int c4 = lane & 7, j = lane >> 3;
  int b = wv >> 15;
  int cnt = hist[wv];
  float ax = 0.f, ay = 0.f, az = 0.f, aw = 0.f;
  if (cnt > 0) {
    int end = offs[wv] + bbase[wv >> 10];  // offs is post-scatter cursor = local end
    int start = end - cnt;
    const float4* ft = reinterpret_cast<const float4*>(featT) + (size_t)b * Nn * 8;
    for (int k = start + j; k < end; k += 8) {
      int n = pidx[k];
      float4 v = ft[n * 8 + c4];
      ax += v.x; ay += v.y; az += v.z; aw += v.w;
    }
    #pragma unroll
    for (int m = 8; m <= 32; m <<= 1) {
      ax += __shfl_xor(ax, m); ay += __shfl_xor(ay, m);
      az += __shfl_xor(az, m); aw += __shfl_xor(aw, m);
    }
    float invc = 1.0f / (float)cnt;
    ax *= invc; ay *= invc; az *= invc; aw *= invc;
  }
  if (j == 0) {
    uint2 o;
    o.x = pack2(ax, ay);
    o.y = pack2(az, aw);
    vox0[(size_t)wv * 8 + c4] = o;
  }
}

// -------- weight permute for 32x32x16 A-frag: w[co][ci][k] -> wt[k][h][lane][e] ----
__global__ void k_twz(const float* __restrict__ w, u16* __restrict__ wt) {
  int i = blockIdx.x * 256 + threadIdx.x;
  if (i >= 27 * 32 * 32) return;
  int e = i & 7, l = (i >> 3) & 63, h = (i >> 9) & 1, k = i >> 10;
  int co = l & 31, ci = h * 16 + ((l >> 5) << 3) + e;
  wt[i] = f2bf(w[(co * 32 + ci) * 27 + k]);
}

// ------- modulation vectors m = silu(cond) @ mw.T + mb (wave-per-row, coalesced) ----
__global__ void k_mods(const float* __restrict__ cond,
                       const float* __restrict__ w1, const float* __restrict__ b1,
                       const float* __restrict__ w2, const float* __restrict__ b2,
                       const float* __restrict__ wp, const float* __restrict__ bp,
                       float* __restrict__ m1, float* __restrict__ m2,
                       float* __restrict__ mp) {
  int blk = blockIdx.x;  // 24 = mat*8 + b
  int mat = blk >> 3, b = blk & 7;
  int t = threadIdx.x;  // 256
  __shared__ float sc[256];
  sc[t] = siluf(cond[b * 256 + t]);
  __syncthreads();
  const float* w = (mat == 0) ? w1 : ((mat == 1) ? w2 : wp);
  const float* bb = (mat == 0) ? b1 : ((mat == 1) ? b2 : bp);
  float* dst = (mat == 0) ? m1 : ((mat == 1) ? m2 : mp);
  int wave = t >> 6, lane = t & 63;
  const float4* w4 = reinterpret_cast<const float4*>(w);
  float4 sv = reinterpret_cast<const float4*>(sc)[lane];
  #pragma unroll
  for (int i = 0; i < 16; ++i) {
    int oo = wave * 16 + i;
    float4 wv = w4[oo * 64 + lane];
    float p = wv.x * sv.x + wv.y * sv.y + wv.z * sv.z + wv.w * sv.w;
    #pragma unroll
    for (int m = 1; m <= 32; m <<= 1) p += __shfl_xor(p, m);
    if (lane == 0) dst[b * 64 + oo] = p + bb[oo];
  }
}

// ------- 3x3x3 conv, bf16 MFMA 32x32x16, X-only LDS (2 blocks/CU), global A-frags,
//         optional fused input affine+silu, fused per-block GN partial stats ---------
template <bool AFF>
__global__ __launch_bounds__(512, 4) void k_conv(
    const u16* __restrict__ in, const u16* __restrict__ wt,
    const float* __restrict__ bias, const float* __restrict__ Ac,
    const float* __restrict__ Bc, u16* __restrict__ out,
    float* __restrict__ pstat) {
  __shared__ uint4 lds_x4[4096];   // 65536 B (4080 used) -> 2 blocks/CU
  int t = threadIdx.x;
  int blk = blockIdx.x;
  int yp = blk & 3, x = (blk >> 2) & 31, b = blk >> 7;
  int y0 = yp * 8;
  size_t bbase = (size_t)b * Vn;

  for (int i = t; i < 4080; i += 512) {
    int col = i / 136, rem = i - col * 136;
    int c4 = rem / 34, r = rem - c4 * 34;
    int dxp = col / 10, yy = col - dxp * 10;
    int gx = x + dxp - 1, gy = y0 + yy - 1, z = r - 1;
    uint4 val = make_uint4(0u, 0u, 0u, 0u);
    if (gx >= 0 && gx < 32 && (unsigned)gy < 32u && (unsigned)z < 32u) {
      val = *reinterpret_cast<const uint4*>(
          in + (bbase + (size_t)((gx * 32 + gy) * 32 + z)) * 32 + c4 * 8);
      if (AFF) {
        float f[8];
        unpack8(val, f);
        float4 A0 = reinterpret_cast<const float4*>(Ac)[b * 8 + c4 * 2];
        float4 A1 = reinterpret_cast<const float4*>(Ac)[b * 8 + c4 * 2 + 1];
        float4 B0 = reinterpret_cast<const float4*>(Bc)[b * 8 + c4 * 2];
        float4 B1 = reinterpret_cast<const float4*>(Bc)[b * 8 + c4 * 2 + 1];
        f[0] = siluf(f[0] * A0.x + B0.x); f[1] = siluf(f[1] * A0.y + B0.y);
        f[2] = siluf(f[2] * A0.z + B0.z); f[3] = siluf(f[3] * A0.w + B0.w);
        f[4] = siluf(f[4] * A1.x + B1.x); f[5] = siluf(f[5] * A1.y + B1.y);
        f[6] = siluf(f[6] * A1.z + B1.z); f[7] = siluf(f[7] * A1.w + B1.w);
        val.x = pack2(f[0], f[1]); val.y = pack2(f[2], f[3]);
        val.z = pack2(f[4], f[5]); val.w = pack2(f[6], f[7]);
      }
    }
    lds_x4[i] = val;
  }
  __syncthreads();

  int w = t >> 6, lane = t & 63;
  int zc = lane & 31, hi = lane >> 5;
  int y = y0 + w;

  f32x16 acc;
  #pragma unroll
  for (int q = 0; q < 4; ++q) {
    float4 bq = *reinterpret_cast<const float4*>(bias + q * 8 + hi * 4);
    acc[q * 4 + 0] = bq.x; acc[q * 4 + 1] = bq.y;
    acc[q * 4 + 2] = bq.z; acc[q * 4 + 3] = bq.w;
  }

  const u16* lx = reinterpret_cast<const u16*>(lds_x4);
  const u16* gw = wt + lane * 8;  // per-lane base; frag k,h at +(k*2+h)*512

  #pragma unroll
  for (int dxp = 0; dxp < 3; ++dxp) {
    #pragma unroll
    for (int dyp = 0; dyp < 3; ++dyp) {
      int col = dxp * 10 + w + dyp;
      #pragma unroll
      for (int dzp = 0; dzp < 3; ++dzp) {
        int k = (dxp * 3 + dyp) * 3 + dzp;
        short8v a0 = *reinterpret_cast<const short8v*>(gw + (k * 2 + 0) * 512);
        short8v a1 = *reinterpret_cast<const short8v*>(gw + (k * 2 + 1) * 512);
        short8v b0 = *reinterpret_cast<const short8v*>(
            lx + ((col * 4 + hi) * 34 + zc + dzp) * 8);
        short8v b1 = *reinterpret_cast<const short8v*>(
            lx + ((col * 4 + 2 + hi) * 34 + zc + dzp) * 8);
        acc = __builtin_amdgcn_mfma_f32_32x32x16_bf16(a0, b0, acc, 0, 0, 0);
        acc = __builtin_amdgcn_mfma_f32_32x32x16_bf16(a1, b1, acc, 0, 0, 0);
      }
    }
  }

  // C/D: col(z)=lane&31, row(co)=(reg&3)+8*(reg>>2)+4*(lane>>5)
  size_t off = (bbase + (size_t)((x * 32 + y) * 32 + zc)) * 32;
  #pragma unroll
  for (int q = 0; q < 4; ++q) {
    uint2 o;
    o.x = pack2(acc[q * 4 + 0], acc[q * 4 + 1]);
    o.y = pack2(acc[q * 4 + 2], acc[q * 4 + 3]);
    *reinterpret_cast<uint2*>(out + off + q * 8 + hi * 4) = o;
  }

  // ---- per-block per-channel partial sum/sumsq (no atomics) ----
  float s16[16], q16[16];
  #pragma unroll
  for (int r = 0; r < 16; ++r) { s16[r] = acc[r]; q16[r] = acc[r] * acc[r]; }
  #pragma unroll
  for (int m = 1; m <= 16; m <<= 1) {
    #pragma unroll
    for (int r = 0; r < 16; ++r) {
      s16[r] += __shfl_xor(s16[r], m);
      q16[r] += __shfl_xor(q16[r], m);
    }
  }
  __syncthreads();  // all waves done reading lds_x4 -> reuse as reduce buffer
  float* sred = reinterpret_cast<float*>(lds_x4);
  if ((lane & 31) == 0) {
    #pragma unroll
    for (int r = 0; r < 16; ++r) {
      int co = (r & 3) + 8 * (r >> 2) + 4 * hi;
      sred[w * 64 + co] = s16[r];
      sred[512 + w * 64 + co] = q16[r];
    }
  }
  __syncthreads();
  if (t < 64) {
    int arr = t >> 5, c = t & 31;
    const float* bp_ = sred + arr * 512 + c;
    float v = bp_[0] + bp_[64] + bp_[128] + bp_[192] +
              bp_[256] + bp_[320] + bp_[384] + bp_[448];
    pstat[blk * 64 + arr * 32 + c] = v;
  }
}

// ------- per-channel sum/sumsq on channel-last bf16, linear chunks (for pxb) -------
__global__ void k_statspx(const u16* __restrict__ x, float* __restrict__ psum,
                          float* __restrict__ psq, int segs) {
  int blk = blockIdx.x;  // B*segs chunks of 4096 uint4
  int b = blk / segs;
  int t = threadIdx.x;
  int c8 = t & 3, vsub = t >> 2;
  float s[8], q[8];
  #pragma unroll
  for (int j = 0; j < 8; ++j) { s[j] = 0.f; q[j] = 0.f; }
  const uint4* xb = reinterpret_cast<const uint4*>(x) + (size_t)blk * 4096;
  for (int it = 0; it < 16; ++it) {
    int v = it * 64 + vsub;
    uint4 u = xb[v * 4 + c8];
    float f[8];
    unpack8(u, f);
    #pragma unroll
    for (int j = 0; j < 8; ++j) { s[j] += f[j]; q[j] += f[j] * f[j]; }
  }
  #pragma unroll
  for (int m = 4; m <= 32; m <<= 1) {
    #pragma unroll
    for (int j = 0; j < 8; ++j) {
      s[j] += __shfl_xor(s[j], m);
      q[j] += __shfl_xor(q[j], m);
    }
  }
  __shared__ float ls[2][4][4][8];
  int wv = t >> 6;
  if ((t & 63) < 4) {
    #pragma unroll
    for (int j = 0; j < 8; ++j) { ls[0][wv][c8][j] = s[j]; ls[1][wv][c8][j] = q[j]; }
  }
  __syncthreads();
  if (t < 64) {
    int arr = t >> 5, c = t & 31;
    float v = ls[arr][0][c >> 3][c & 7] + ls[arr][1][c >> 3][c & 7] +
              ls[arr][2][c >> 3][c & 7] + ls[arr][3][c >> 3][c & 7];
    atomicAdd((arr == 0 ? psum : psq) + b * 32 + c, v);
  }
}

// ------- AdaGN affine coefs (stage 1) from conv per-block partials ----------------
__global__ void k_coef1(const float* __restrict__ pstat, const float* __restrict__ mod,
                        const float* __restrict__ g, const float* __restrict__ bgn,
                        float* __restrict__ A, float* __restrict__ Bc) {
  int t = threadIdx.x;  // 256 = B*C
  int b = t >> 5, c = t & 31;
  float cs = 0.f, cq = 0.f;
  const float* p = pstat + (size_t)b * 128 * 64;
  for (int i = 0; i < 128; ++i) {
    cs += p[i * 64 + c];
    cq += p[i * 64 + 32 + c];
  }
  __shared__ float ls[256], lq[256];
  ls[t] = cs; lq[t] = cq;
  __syncthreads();
  int gb = t & ~3;
  float s4 = ls[gb] + ls[gb + 1] + ls[gb + 2] + ls[gb + 3];
  float q4 = lq[gb] + lq[gb + 1] + lq[gb + 2] + lq[gb + 3];
  const float cntf = 4.0f * (float)Vn;
  float mean = s4 / cntf;
  float var = q4 / cntf - mean * mean;
  float rstd = rsqrtf(var + 1e-5f);
  float scale = mod[b * 64 + c], shift = mod[b * 64 + 32 + c];
  A[t] = rstd * g[c] * scale;
  Bc[t] = (bgn[c] - mean * rstd * g[c]) * scale + shift;
}

// ------- AdaGN stage 2 + SE from conv partials -> gather affine S,T ---------------
__global__ void k_coef2(const float* __restrict__ pstat, const float* __restrict__ mod,
                        const float* __restrict__ g, const float* __restrict__ bgn,
                        const float* __restrict__ sw1, const float* __restrict__ sw2,
                        float* __restrict__ S, float* __restrict__ T) {
  __shared__ float zm[8][32];
  __shared__ float hh[8][4];
  __shared__ float ls[256], lq[256];
  int t = threadIdx.x;  // 256 = B*C
  int b = t >> 5, c = t & 31;
  float cs = 0.f, cq = 0.f;
  const float* p = pstat + (size_t)b * 128 * 64;
  for (int i = 0; i < 128; ++i) {
    cs += p[i * 64 + c];
    cq += p[i * 64 + 32 + c];
  }
  ls[t] = cs; lq[t] = cq;
  __syncthreads();
  int gb = t & ~3;
  float s4 = ls[gb] + ls[gb + 1] + ls[gb + 2] + ls[gb + 3];
  float q4 = lq[gb] + lq[gb + 1] + lq[gb + 2] + lq[gb + 3];
  const float cntf = 4.0f * (float)Vn;
  float mean = s4 / cntf;
  float var = q4 / cntf - mean * mean;
  float rstd = rsqrtf(var + 1e-5f);
  float scale = mod[b * 64 + c], shift = mod[b * 64 + 32 + c];
  float A = rstd * g[c] * scale;
  float Bv = (bgn[c] - mean * rstd * g[c]) * scale + shift;
  float chmean = cs / (float)Vn;
  zm[b][c] = A * chmean + Bv;
  __syncthreads();
  if (t < 32) {
    int b2 = t >> 2, j = t & 3;
    float h = 0;
    for (int cc = 0; cc < 32; ++cc) h += sw1[j * 32 + cc] * zm[b2][cc];
    hh[b2][j] = fmaxf(h, 0.f);
  }
  __syncthreads();
  float sig = 0;
  for (int j = 0; j < 4; ++j) sig += sw2[c * 4 + j] * hh[b][j];
  sig = 1.0f / (1.0f + __expf(-sig));
  S[t] = A * sig;
  T[t] = Bv * sig;
}

// ---------------- point-branch affine coefficients ----------------
__global__ void k_coefp(const float* __restrict__ psum, const float* __restrict__ psq,
                        const float* __restrict__ mod, const float* __restrict__ g,
                        const float* __restrict__ bgn, float* __restrict__ A,
                        float* __restrict__ Bc) {
  __shared__ float ls[256], lq[256];
  int t = threadIdx.x;  // 256 = B*C
  int b = t >> 5, c = t & 31;
  ls[t] = psum[t]; lq[t] = psq[t];
  __syncthreads();
  int gb = t & ~3;
  float s4 = ls[gb] + ls[gb + 1] + ls[gb + 2] + ls[gb + 3];
  float q4 = lq[gb] + lq[gb + 1] + lq[gb + 2] + lq[gb + 3];
  const float cntf = 4.0f * (float)Nn;
  float m = s4 / cntf;
  float var = q4 / cntf - m * m;
  float r = rsqrtf(var + 1e-5f);
  float scale = mod[b * 64 + c], shift = mod[b * 64 + 32 + c];
  A[t] = r * g[c] * scale;
  Bc[t] = (bgn[c] - m * r * g[c]) * scale + shift;
}

// ------- fused: trilinear devox (affine S,T) + silu(px*Ap+Bp) point branch --------
__global__ void k_devoxfinal(const u16* __restrict__ vox, const float* __restrict__ nc,
                             const u16* __restrict__ pxb, const float* __restrict__ S,
                             const float* __restrict__ T, const float* __restrict__ Ap,
                             const float* __restrict__ Bp, float* __restrict__ out) {
  int i = blockIdx.x * 256 + threadIdx.x;  // B*N
  int b = i >> 14, n = i & (Nn - 1);
  const float* ncb = nc + (size_t)b * 3 * Nn;
  float fx = ncb[n], fy = ncb[Nn + n], fz = ncb[2 * Nn + n];
  float lxf = floorf(fx), lyf = floorf(fy), lzf = floorf(fz);
  float wx1 = fx - lxf, wy1 = fy - lyf, wz1 = fz - lzf;
  int lx = (int)lxf, ly = (int)lyf, lz = (int)lzf;
  int hx = min(lx + 1, 31), hy = min(ly + 1, 31), hz = min(lz + 1, 31);
  float a[32];
  #pragma unroll
  for (int c = 0; c < 32; ++c) a[c] = 0.f;
  for (int corner = 0; corner < 8; ++corner) {
    int cx = (corner & 4) ? hx : lx;
    int cy = (corner & 2) ? hy : ly;
    int cz = (corner & 1) ? hz : lz;
    float ww = ((corner & 4) ? wx1 : 1.f - wx1) *
               ((corner & 2) ? wy1 : 1.f - wy1) *
               ((corner & 1) ? wz1 : 1.f - wz1);
    const uint4* p = reinterpret_cast<const uint4*>(
        vox + ((size_t)b * Vn + (size_t)((cx * 32 + cy) * 32 + cz)) * 32);
    #pragma unroll
    for (int qq = 0; qq < 4; ++qq) {
      float f[8];
      unpack8(p[qq], f);
      #pragma unroll
      for (int j = 0; j < 8; ++j) a[qq * 8 + j] += ww * f[j];
    }
  }
  const uint4* pp = reinterpret_cast<const uint4*>(pxb) + (size_t)i * 4;
  float* o = out + (size_t)b * 32 * Nn + n;
  #pragma unroll
  for (int qq = 0; qq < 4; ++qq) {
    float pf[8];
    unpack8(pp[qq], pf);
    #pragma unroll
    for (int j = 0; j < 8; ++j) {
      int c = qq * 8 + j;
      float y = pf[j] * Ap[b * 32 + c] + Bp[b * 32 + c];
      o[(size_t)c * Nn] = a[c] * S[b * 32 + c] + T[b * 32 + c] + siluf(y);
    }
  }
}

}  // namespace

extern "C" void kernel_launch(void* const* d_in, const int* in_sizes, int n_in,
                              void* d_out, int out_size, void* d_ws, size_t ws_size,
                              hipStream_t stream) {
  (void)in_sizes; (void)n_in; (void)out_size; (void)ws_size;
  const float* features = (const float*)d_in[0];
  const float* coords = (const float*)d_in[1];
  const float* condition = (const float*)d_in[2];
  const float* conv1_w = (const float*)d_in[3];
  const float* conv1_b = (const float*)d_in[4];
  const float* gn1_g = (const float*)d_in[5];
  const float* gn1_b = (const float*)d_in[6];
  const float* mod1_w = (const float*)d_in[7];
  const float* mod1_b = (const float*)d_in[8];
  const float* conv2_w = (const float*)d_in[9];
  const float* conv2_b = (const float*)d_in[10];
  const float* gn2_g = (const float*)d_in[11];
  const float* gn2_b = (const float*)d_in[12];
  const float* mod2_w = (const float*)d_in[13];
  const float* mod2_b = (const float*)d_in[14];
  const float* se_w1 = (const float*)d_in[15];
  const float* se_w2 = (const float*)d_in[16];
  const float* pc_w = (const float*)d_in[17];
  const float* pc_b = (const float*)d_in[18];
  const float* gnp_g = (const float*)d_in[19];
  const float* gnp_b = (const float*)d_in[20];
  const float* modp_w = (const float*)d_in[21];
  const float* modp_b = (const float*)d_in[22];

  char* w = (char*)d_ws;
  // R0a (16.8 MB): featT f32 (pxlin -> voxavg), then vox1 bf16 (conv1 -> conv2)
  float* featT = (float*)w;
  u16* vox1 = (u16*)w;
  w += 16777216;
  u16* vox2 = (u16*)w; w += 16777216;   // conv2 out -> devoxfinal
  u16* vox0 = (u16*)w; w += 16777216;   // voxavg -> conv1
  u16* pxb = (u16*)w;  w += 8388608;    // point-branch bf16 CL (pxlin -> devoxfinal)
  int* hist = (int*)w;  w += 1048576;   // memset block: hist, psump, psqp, csum, cmax
  float* psump = (float*)w; w += 1024;
  float* psqp = (float*)w;  w += 1024;
  float* csum = (float*)w;  w += 128;
  int* cmax = (int*)w;      w += 64;
  int* offs = (int*)w;  w += 1048576;
  int* bsum = (int*)w;  w += 1024;
  int* bbase = (int*)w; w += 1024;
  int* pidx = (int*)w;  w += 524288;
  float* ncb = (float*)w;   w += 1572864;
  int* vidx = (int*)w;      w += 524288;
  u16* wt1b = (u16*)w;      w += 55296;
  u16* wt2b = (u16*)w;      w += 55296;
  float* pstat1 = (float*)w; w += 262144;
  float* pstat2 = (float*)w; w += 262144;
  float* m1 = (float*)w;    w += 2048;
  float* m2 = (float*)w;    w += 2048;
  float* mp = (float*)w;    w += 2048;
  float* A1 = (float*)w;    w += 1024;
  float* B1 = (float*)w;    w += 1024;
  float* Sc = (float*)w;    w += 1024;
  float* Tc = (float*)w;    w += 1024;
  float* Ap = (float*)w;    w += 1024;
  float* Bp = (float*)w;    w += 1024;
  float* out = (float*)d_out;

  hipMemsetAsync(hist, 0, 1048576 + 1024 + 1024 + 128 + 64, stream);

  k_pxlin<<<Bn * 64, 256, 0, stream>>>(features, pc_w, pc_b, featT, pxb);
  k_cpart1<<<Bn * 8, 256, 0, stream>>>(coords, csum);
  k_twz<<<108, 256, 0, stream>>>(conv1_w, wt1b);
  k_twz<<<108, 256, 0, stream>>>(conv2_w, wt2b);
  k_mods<<<24, 256, 0, stream>>>(condition, mod1_w, mod1_b, mod2_w, mod2_b,
                                 modp_w, modp_b, m1, m2, mp);
  k_statspx<<<Bn * 16, 256, 0, stream>>>(pxb, psump, psqp, 16);
  k_coefp<<<1, 256, 0, stream>>>(psump, psqp, mp, gnp_g, gnp_b, Ap, Bp);
  k_cpart2<<<Bn * 8, 256, 0, stream>>>(coords, csum, cmax);
  k_cfinal<<<(Bn * Nn) / 256, 256, 0, stream>>>(coords, csum, cmax, ncb, vidx, hist);
  k_scan1<<<256, 256, 0, stream>>>(hist, offs, bsum);
  k_scan2<<<1, 256, 0, stream>>>(bsum, bbase);
  k_sortidx<<<(Bn * Nn) / 256, 256, 0, stream>>>(vidx, offs, bbase, pidx);
  k_voxavg<<<(Bn * Vn) / 4, 256, 0, stream>>>(hist, offs, bbase, pidx, featT,
                                              (uint2*)vox0);
  k_conv<false><<<1024, 512, 0, stream>>>(vox0, wt1b, conv1_b, nullptr, nullptr,
                                          vox1, pstat1);
  k_coef1<<<1, 256, 0, stream>>>(pstat1, m1, gn1_g, gn1_b, A1, B1);
  k_conv<true><<<1024, 512, 0, stream>>>(vox1, wt2b, conv2_b, A1, B1, vox2, pstat2);
  k_coef2<<<1, 256, 0, stream>>>(pstat2, m2, gn2_g, gn2_b, se_w1, se_w2, Sc, Tc);
  k_devoxfinal<<<(Bn * Nn) / 256, 256, 0, stream>>>(vox2, ncb, pxb, Sc, Tc, Ap, Bp, out);
}

// Round 10
// 217.255 us; speedup vs baseline: 1.1078x; 1.0224x over previous
//
#include <hip/hip_runtime.h>
#include <math.h>

#define DEV_INLINE __device__ __forceinline__

namespace {

typedef unsigned short u16;
typedef unsigned int u32;
typedef __attribute__((ext_vector_type(8))) short short8v;
typedef __attribute__((ext_vector_type(16))) float f32x16;

constexpr int Bn = 8, Cn = 32, Nn = 16384, Rn = 32, Vn = Rn * Rn * Rn;

DEV_INLINE float siluf(float x) { return x / (1.0f + __expf(-x)); }
DEV_INLINE float bf2f(u16 u) { union { u32 i; float f; } x; x.i = (u32)u << 16; return x.f; }
DEV_INLINE u16 f2bf(float f) {
  union { float f; u32 i; } x; x.f = f;
  return (u16)((x.i + 0x7FFFu + ((x.i >> 16) & 1u)) >> 16);
}
DEV_INLINE u32 pack2(float a, float b) { return (u32)f2bf(a) | ((u32)f2bf(b) << 16); }
DEV_INLINE void unpack8(uint4 u, float* f) {
  f[0] = bf2f(u.x & 0xffff); f[1] = bf2f(u.x >> 16);
  f[2] = bf2f(u.y & 0xffff); f[3] = bf2f(u.y >> 16);
  f[4] = bf2f(u.z & 0xffff); f[5] = bf2f(u.z >> 16);
  f[6] = bf2f(u.w & 0xffff); f[7] = bf2f(u.w >> 16);
}

// ---------------- coords stage 1: partial xyz sums ----------------
__global__ void k_cpart1(const float* __restrict__ coords, float* __restrict__ csum) {
  int blk = blockIdx.x;  // B*8
  int b = blk >> 3, s = blk & 7;
  int t = threadIdx.x;
  const float* cb = coords + (size_t)b * 3 * Nn;
  int n0 = s * 2048;
  float sx = 0.f, sy = 0.f, sz = 0.f;
  for (int n = n0 + t; n < n0 + 2048; n += 256) {
    sx += cb[n]; sy += cb[Nn + n]; sz += cb[2 * Nn + n];
  }
  #pragma unroll
  for (int m = 1; m <= 32; m <<= 1) {
    sx += __shfl_xor(sx, m); sy += __shfl_xor(sy, m); sz += __shfl_xor(sz, m);
  }
  __shared__ float rs[3][4];
  if ((t & 63) == 0) { rs[0][t >> 6] = sx; rs[1][t >> 6] = sy; rs[2][t >> 6] = sz; }
  __syncthreads();
  if (t < 3) atomicAdd(&csum[b * 4 + t], rs[t][0] + rs[t][1] + rs[t][2] + rs[t][3]);
}

// ---------------- coords stage 2: partial max of squared norm ----------------
__global__ void k_cpart2(const float* __restrict__ coords, const float* __restrict__ csum,
                         int* __restrict__ cmax) {
  int blk = blockIdx.x;  // B*8
  int b = blk >> 3, s = blk & 7;
  int t = threadIdx.x;
  const float* cb = coords + (size_t)b * 3 * Nn;
  const float invn = 1.0f / (float)Nn;
  float mx = csum[b * 4] * invn, my = csum[b * 4 + 1] * invn, mz = csum[b * 4 + 2] * invn;
  int n0 = s * 2048;
  float mq = 0.f;
  for (int n = n0 + t; n < n0 + 2048; n += 256) {
    float x = cb[n] - mx, y = cb[Nn + n] - my, z = cb[2 * Nn + n] - mz;
    mq = fmaxf(mq, x * x + y * y + z * z);
  }
  #pragma unroll
  for (int m = 1; m <= 32; m <<= 1) mq = fmaxf(mq, __shfl_xor(mq, m));
  __shared__ float rm[4];
  if ((t & 63) == 0) rm[t >> 6] = mq;
  __syncthreads();
  if (t == 0) {
    float v = fmaxf(fmaxf(rm[0], rm[1]), fmaxf(rm[2], rm[3]));
    atomicMax(cmax + b, __float_as_int(v));  // values >= 0 -> int-bits order ok
  }
}

// ---------------- coords stage 3: nc, voxel idx, histogram ----------------
__global__ void k_cfinal(const float* __restrict__ coords, const float* __restrict__ csum,
                         const int* __restrict__ cmax, float* __restrict__ nc,
                         int* __restrict__ vidx, int* __restrict__ hist) {
  int i = blockIdx.x * 256 + threadIdx.x;  // B*N
  int b = i >> 14, n = i & (Nn - 1);
  const float* cb = coords + (size_t)b * 3 * Nn;
  const float invn = 1.0f / (float)Nn;
  float mx = csum[b * 4] * invn, my = csum[b * 4 + 1] * invn, mz = csum[b * 4 + 2] * invn;
  float inv = 1.0f / (2.0f * sqrtf(__int_as_float(cmax[b])));
  float x = (cb[n] - mx) * inv + 0.5f;
  float y = (cb[Nn + n] - my) * inv + 0.5f;
  float z = (cb[2 * Nn + n] - mz) * inv + 0.5f;
  x = fminf(fmaxf(x * (float)Rn, 0.f), (float)(Rn - 1));
  y = fminf(fmaxf(y * (float)Rn, 0.f), (float)(Rn - 1));
  z = fminf(fmaxf(z * (float)Rn, 0.f), (float)(Rn - 1));
  float* ncb = nc + (size_t)b * 3 * Nn;
  ncb[n] = x; ncb[Nn + n] = y; ncb[2 * Nn + n] = z;
  int vx = (int)rintf(x), vy = (int)rintf(y), vz = (int)rintf(z);
  int v = (vx * Rn + vy) * Rn + vz;
  vidx[i] = v;
  atomicAdd(&hist[b * Vn + v], 1);
}

// ------- fused point branch: featT (f32 transpose) + px = feat@W.T+b (bf16 CL) -----
__global__ __launch_bounds__(256, 2) void k_pxlin(
    const float* __restrict__ feat, const float* __restrict__ w,
    const float* __restrict__ bias, float* __restrict__ featT,
    u16* __restrict__ pxb) {
  __shared__ float lw[1024];
  __shared__ float lb[32];
  __shared__ float lbuf[256 * 33];  // 33.8 KB transpose buffer (reused as u32)
  int t = threadIdx.x;
  for (int i = t; i < 1024; i += 256) lw[i] = w[i];
  if (t < 32) lb[t] = bias[t];
  int blk = blockIdx.x;  // B*64
  int b = blk >> 6, tile = blk & 63;
  int n0 = tile * 256, n = n0 + t;
  float fr[32];
  const float* fb = feat + (size_t)b * 32 * Nn + n;
  #pragma unroll
  for (int ci = 0; ci < 32; ++ci) {
    fr[ci] = fb[(size_t)ci * Nn];
    lbuf[t * 33 + ci] = fr[ci];
  }
  __syncthreads();
  float* ftb = featT + ((size_t)b * Nn + n0) * 32;
  #pragma unroll
  for (int j = 0; j < 32; ++j) {
    int idx = j * 256 + t;
    ftb[idx] = lbuf[(idx >> 5) * 33 + (idx & 31)];  // coalesced 1KB store
  }
  __syncthreads();
  u32* lbu = reinterpret_cast<u32*>(lbuf);
  #pragma unroll
  for (int p2 = 0; p2 < 16; ++p2) {
    int co0 = p2 * 2;
    float a0 = lb[co0], a1 = lb[co0 + 1];
    #pragma unroll
    for (int ci = 0; ci < 32; ++ci) {
      a0 += lw[co0 * 32 + ci] * fr[ci];
      a1 += lw[(co0 + 1) * 32 + ci] * fr[ci];
    }
    lbu[t * 17 + p2] = pack2(a0, a1);
  }
  __syncthreads();
  u32* pxu = reinterpret_cast<u32*>(pxb) + ((size_t)b * Nn + n0) * 16;
  #pragma unroll
  for (int j = 0; j < 16; ++j) {
    int idx = j * 256 + t;
    pxu[idx] = lbu[(idx >> 4) * 17 + (idx & 15)];
  }
}

// ---------------- scan stage 1: per-1024-chunk exclusive prefix ----------------
__global__ void k_scan1(const int* __restrict__ hist, int* __restrict__ offs,
                        int* __restrict__ bsum) {
  __shared__ int sd[256];
  int t = threadIdx.x, blk = blockIdx.x;  // 256 blocks
  int4 h = reinterpret_cast<const int4*>(hist)[blk * 256 + t];
  int s = h.x + h.y + h.z + h.w;
  sd[t] = s; __syncthreads();
  for (int off = 1; off < 256; off <<= 1) {
    int add = (t >= off) ? sd[t - off] : 0;
    __syncthreads();
    sd[t] += add;
    __syncthreads();
  }
  int excl = sd[t] - s;
  int4 o;
  o.x = excl; o.y = excl + h.x; o.z = o.y + h.y; o.w = o.z + h.z;
  reinterpret_cast<int4*>(offs)[blk * 256 + t] = o;
  if (t == 0) bsum[blk] = sd[255];
}

// ---------------- scan stage 2: exclusive scan of 256 block sums ----------------
__global__ void k_scan2(const int* __restrict__ bsum, int* __restrict__ bbase) {
  __shared__ int sd[256];
  int t = threadIdx.x;
  int s = bsum[t];
  sd[t] = s; __syncthreads();
  for (int off = 1; off < 256; off <<= 1) {
    int add = (t >= off) ? sd[t - off] : 0;
    __syncthreads();
    sd[t] += add;
    __syncthreads();
  }
  bbase[t] = sd[t] - s;
}

// ---------------- cursor-scatter point indices into sorted order ----------------
__global__ void k_sortidx(const int* __restrict__ vidx, int* __restrict__ offs,
                          const int* __restrict__ bbase, int* __restrict__ pidx) {
  int i = blockIdx.x * 256 + threadIdx.x;  // B*N
  int b = i >> 14, n = i & (Nn - 1);
  int g = b * Vn + vidx[i];
  int p = atomicAdd(&offs[g], 1) + bbase[g >> 10];
  pidx[p] = n;
}

// ---------------- per-voxel average -> bf16 channel-last vox0 ----------------
__global__ void k_voxavg(const int* __restrict__ hist, const int* __restrict__ offs,
                         const int* __restrict__ bbase, const int* __restrict__ pidx,
                         const float* __restrict__ featT, uint2* __restrict__ vox0) {
  int t = threadIdx.x;
  int wv = blockIdx.x * 4 + (t >> 6);  // global voxel id, B*V total
  int lane = t & 63;
  int c4 = lane & 7, j = lane >> 3;
  int b = wv >> 15;
  int cnt = hist[wv];
  float ax = 0.f, ay = 0.f, az = 0.f, aw = 0.f;
  if (cnt > 0) {
    int end = offs[wv] + bbase[wv >> 10];  // offs is post-scatter cursor = local end
    int start = end - cnt;
    const float4* ft = reinterpret_cast<const float4*>(featT) + (size_t)b * Nn * 8;
    for (int k = start + j; k < end; k += 8) {
      int n = pidx[k];
      float4 v = ft[n * 8 + c4];
      ax += v.x; ay += v.y; az += v.z; aw += v.w;
    }
    #pragma unroll
    for (int m = 8; m <= 32; m <<= 1) {
      ax += __shfl_xor(ax, m); ay += __shfl_xor(ay, m);
      az += __shfl_xor(az, m); aw += __shfl_xor(aw, m);
    }
    float invc = 1.0f / (float)cnt;
    ax *= invc; ay *= invc; az *= invc; aw *= invc;
  }
  if (j == 0) {
    uint2 o;
    o.x = pack2(ax, ay);
    o.y = pack2(az, aw);
    vox0[(size_t)wv * 8 + c4] = o;
  }
}

// -------- weight permute for 32x32x16 A-frag: w[co][ci][k] -> wt[k][h][lane][e] ----
__global__ void k_twz(const float* __restrict__ w, u16* __restrict__ wt) {
  int i = blockIdx.x * 256 + threadIdx.x;
  if (i >= 27 * 32 * 32) return;
  int e = i & 7, l = (i >> 3) & 63, h = (i >> 9) & 1, k = i >> 10;
  int co = l & 31, ci = h * 16 + ((l >> 5) << 3) + e;
  wt[i] = f2bf(w[(co * 32 + ci) * 27 + k]);
}

// ------- modulation vectors m = silu(cond) @ mw.T + mb (wave-per-row, coalesced) ----
__global__ void k_mods(const float* __restrict__ cond,
                       const float* __restrict__ w1, const float* __restrict__ b1,
                       const float* __restrict__ w2, const float* __restrict__ b2,
                       const float* __restrict__ wp, const float* __restrict__ bp,
                       float* __restrict__ m1, float* __restrict__ m2,
                       float* __restrict__ mp) {
  int blk = blockIdx.x;  // 24 = mat*8 + b
  int mat = blk >> 3, b = blk & 7;
  int t = threadIdx.x;  // 256
  __shared__ float sc[256];
  sc[t] = siluf(cond[b * 256 + t]);
  __syncthreads();
  const float* w = (mat == 0) ? w1 : ((mat == 1) ? w2 : wp);
  const float* bb = (mat == 0) ? b1 : ((mat == 1) ? b2 : bp);
  float* dst = (mat == 0) ? m1 : ((mat == 1) ? m2 : mp);
  int wave = t >> 6, lane = t & 63;
  const float4* w4 = reinterpret_cast<const float4*>(w);
  float4 sv = reinterpret_cast<const float4*>(sc)[lane];
  #pragma unroll
  for (int i = 0; i < 16; ++i) {
    int oo = wave * 16 + i;
    float4 wv = w4[oo * 64 + lane];
    float p = wv.x * sv.x + wv.y * sv.y + wv.z * sv.z + wv.w * sv.w;
    #pragma unroll
    for (int m = 1; m <= 32; m <<= 1) p += __shfl_xor(p, m);
    if (lane == 0) dst[b * 64 + oo] = p + bb[oo];
  }
}

// ---- staging helpers for persistent conv (4-y tile: 18 cols x 4 c4 x 34 r) ----
template <bool AFF>
DEV_INLINE void stage_load(const u16* __restrict__ in, size_t bbase, int x, int ytn,
                           int t, const float* __restrict__ Ac,
                           const float* __restrict__ Bc, int b, uint4* sv) {
  #pragma unroll
  for (int it = 0; it < 5; ++it) {
    int i = it * 512 + t;
    uint4 val = make_uint4(0u, 0u, 0u, 0u);
    if (i < 2448) {
      int col = i / 136, rem = i - col * 136;
      int c4 = rem / 34, r = rem - c4 * 34;
      int dxp = col / 6, yy = col - dxp * 6;
      int gx = x + dxp - 1, gy = ytn * 4 + yy - 1, z = r - 1;
      if ((unsigned)gx < 32u && (unsigned)gy < 32u && (unsigned)z < 32u) {
        val = *reinterpret_cast<const uint4*>(
            in + (bbase + (size_t)((gx * 32 + gy) * 32 + z)) * 32 + c4 * 8);
        if (AFF) {
          float f[8];
          unpack8(val, f);
          float4 A0 = reinterpret_cast<const float4*>(Ac)[b * 8 + c4 * 2];
          float4 A1 = reinterpret_cast<const float4*>(Ac)[b * 8 + c4 * 2 + 1];
          float4 B0 = reinterpret_cast<const float4*>(Bc)[b * 8 + c4 * 2];
          float4 B1 = reinterpret_cast<const float4*>(Bc)[b * 8 + c4 * 2 + 1];
          f[0] = siluf(f[0] * A0.x + B0.x); f[1] = siluf(f[1] * A0.y + B0.y);
          f[2] = siluf(f[2] * A0.z + B0.z); f[3] = siluf(f[3] * A0.w + B0.w);
          f[4] = siluf(f[4] * A1.x + B1.x); f[5] = siluf(f[5] * A1.y + B1.y);
          f[6] = siluf(f[6] * A1.z + B1.z); f[7] = siluf(f[7] * A1.w + B1.w);
          val.x = pack2(f[0], f[1]); val.y = pack2(f[2], f[3]);
          val.z = pack2(f[4], f[5]); val.w = pack2(f[6], f[7]);
        }
      }
    }
    sv[it] = val;
  }
}

DEV_INLINE void stage_store(uint4* __restrict__ dst, int t, const uint4* sv) {
  #pragma unroll
  for (int it = 0; it < 5; ++it) {
    int i = it * 512 + t;
    if (i < 2448) dst[i] = sv[it];
  }
}

// ------- persistent 3x3x3 conv: W in registers (k-half split), double-buffered X,
//         bf16 MFMA 32x32x16, fused input affine+silu, fused GN partial stats -------
// Grid 256 = (b, x). 8 waves = 4 y-slots x 2 k-halves; loop over 8 tiles of 4 y.
template <bool AFF>
__global__ __launch_bounds__(512, 2) void k_conv(
    const u16* __restrict__ in, const u16* __restrict__ wt,
    const float* __restrict__ bias, const float* __restrict__ Ac,
    const float* __restrict__ Bc, u16* __restrict__ out,
    float* __restrict__ pstat) {
  __shared__ uint4 lds_x[4896];  // 2 x 2448 uint4 = 78336 B
  __shared__ float red[4096];    // acc exchange [ys][reg][lane] = 16 KB
  int t = threadIdx.x;
  int blk = blockIdx.x;  // 256 = b*32 + x
  int x = blk & 31, b = blk >> 5;
  size_t bbase = (size_t)b * Vn;
  int w = t >> 6, lane = t & 63;
  int ys = w >> 1, h = w & 1;
  int zc = lane & 31, hi = lane >> 5;

  // W fragments for this k-half into registers (27 x 16B/lane, coalesced)
  short8v wreg[27];
  #pragma unroll
  for (int k = 0; k < 27; ++k)
    wreg[k] = *reinterpret_cast<const short8v*>(wt + ((size_t)(k * 2 + h) * 64 + lane) * 8);

  uint4 sv[5];
  stage_load<AFF>(in, bbase, x, 0, t, Ac, Bc, b, sv);
  stage_store(lds_x, t, sv);
  __syncthreads();

  float s16[16], q16[16];
  #pragma unroll
  for (int r = 0; r < 16; ++r) { s16[r] = 0.f; q16[r] = 0.f; }

  int cur = 0;
  for (int yt = 0; yt < 8; ++yt) {
    if (yt < 7) stage_load<AFF>(in, bbase, x, yt + 1, t, Ac, Bc, b, sv);

    f32x16 acc;
    #pragma unroll
    for (int r = 0; r < 16; ++r) acc[r] = 0.f;
    if (h == 0) {
      #pragma unroll
      for (int q = 0; q < 4; ++q) {
        float4 bq = *reinterpret_cast<const float4*>(bias + q * 8 + hi * 4);
        acc[q * 4 + 0] = bq.x; acc[q * 4 + 1] = bq.y;
        acc[q * 4 + 2] = bq.z; acc[q * 4 + 3] = bq.w;
      }
    }

    const u16* lx = reinterpret_cast<const u16*>(lds_x + cur * 2448);
    int cbase = 2 * h + hi;
    #pragma unroll
    for (int dxp = 0; dxp < 3; ++dxp) {
      #pragma unroll
      for (int dyp = 0; dyp < 3; ++dyp) {
        int col = dxp * 6 + ys + dyp;
        const u16* lcol = lx + ((col * 4 + cbase) * 34 + zc) * 8;
        #pragma unroll
        for (int dzp = 0; dzp < 3; ++dzp) {
          int k = (dxp * 3 + dyp) * 3 + dzp;
          short8v bb = *reinterpret_cast<const short8v*>(lcol + dzp * 8);
          acc = __builtin_amdgcn_mfma_f32_32x32x16_bf16(wreg[k], bb, acc, 0, 0, 0);
        }
      }
    }

    if (h == 1) {
      #pragma unroll
      for (int r = 0; r < 16; ++r) red[ys * 1024 + r * 64 + lane] = acc[r];
    }
    __syncthreads();
    if (h == 0) {
      #pragma unroll
      for (int r = 0; r < 16; ++r) acc[r] += red[ys * 1024 + r * 64 + lane];
      int y = yt * 4 + ys;
      // C/D: col(z)=lane&31, row(co)=(reg&3)+8*(reg>>2)+4*hi
      size_t off = (bbase + (size_t)((x * 32 + y) * 32 + zc)) * 32;
      #pragma unroll
      for (int q = 0; q < 4; ++q) {
        uint2 o;
        o.x = pack2(acc[q * 4 + 0], acc[q * 4 + 1]);
        o.y = pack2(acc[q * 4 + 2], acc[q * 4 + 3]);
        *reinterpret_cast<uint2*>(out + off + q * 8 + hi * 4) = o;
      }
      #pragma unroll
      for (int r = 0; r < 16; ++r) { s16[r] += acc[r]; q16[r] += acc[r] * acc[r]; }
    }
    if (yt < 7) stage_store(lds_x + (cur ^ 1) * 2448, t, sv);
    __syncthreads();
    cur ^= 1;
  }

  // ---- block GN partial stats: reduce h==0 waves' register accumulators ----
  if (h == 0) {
    #pragma unroll
    for (int m = 1; m <= 16; m <<= 1) {
      #pragma unroll
      for (int r = 0; r < 16; ++r) {
        s16[r] += __shfl_xor(s16[r], m);
        q16[r] += __shfl_xor(q16[r], m);
      }
    }
    if ((lane & 31) == 0) {
      #pragma unroll
      for (int r = 0; r < 16; ++r) {
        int co = (r & 3) + 8 * (r >> 2) + 4 * hi;
        red[ys * 64 + co] = s16[r];
        red[256 + ys * 64 + co] = q16[r];
      }
    }
  }
  __syncthreads();
  if (t < 64) {
    int arr = t >> 5, c = t & 31;
    const float* pr = red + arr * 256 + c;
    float v = pr[0] + pr[64] + pr[128] + pr[192];
    pstat[blk * 64 + arr * 32 + c] = v;
  }
}

// ------- per-channel sum/sumsq on channel-last bf16, linear chunks (for pxb) -------
__global__ void k_statspx(const u16* __restrict__ x, float* __restrict__ psum,
                          float* __restrict__ psq, int segs) {
  int blk = blockIdx.x;  // B*segs chunks of 4096 uint4
  int b = blk / segs;
  int t = threadIdx.x;
  int c8 = t & 3, vsub = t >> 2;
  float s[8], q[8];
  #pragma unroll
  for (int j = 0; j < 8; ++j) { s[j] = 0.f; q[j] = 0.f; }
  const uint4* xb = reinterpret_cast<const uint4*>(x) + (size_t)blk * 4096;
  for (int it = 0; it < 16; ++it) {
    int v = it * 64 + vsub;
    uint4 u = xb[v * 4 + c8];
    float f[8];
    unpack8(u, f);
    #pragma unroll
    for (int j = 0; j < 8; ++j) { s[j] += f[j]; q[j] += f[j] * f[j]; }
  }
  #pragma unroll
  for (int m = 4; m <= 32; m <<= 1) {
    #pragma unroll
    for (int j = 0; j < 8; ++j) {
      s[j] += __shfl_xor(s[j], m);
      q[j] += __shfl_xor(q[j], m);
    }
  }
  __shared__ float ls[2][4][4][8];
  int wv = t >> 6;
  if ((t & 63) < 4) {
    #pragma unroll
    for (int j = 0; j < 8; ++j) { ls[0][wv][c8][j] = s[j]; ls[1][wv][c8][j] = q[j]; }
  }
  __syncthreads();
  if (t < 64) {
    int arr = t >> 5, c = t & 31;
    float v = ls[arr][0][c >> 3][c & 7] + ls[arr][1][c >> 3][c & 7] +
              ls[arr][2][c >> 3][c & 7] + ls[arr][3][c >> 3][c & 7];
    atomicAdd((arr == 0 ? psum : psq) + b * 32 + c, v);
  }
}

// ------- AdaGN affine coefs (stage 1) from conv per-block partials ----------------
__global__ void k_coef1(const float* __restrict__ pstat, const float* __restrict__ mod,
                        const float* __restrict__ g, const float* __restrict__ bgn,
                        float* __restrict__ A, float* __restrict__ Bc) {
  int t = threadIdx.x;  // 256 = B*C
  int b = t >> 5, c = t & 31;
  float cs = 0.f, cq = 0.f;
  const float* p = pstat + (size_t)b * 32 * 64;
  for (int i = 0; i < 32; ++i) {
    cs += p[i * 64 + c];
    cq += p[i * 64 + 32 + c];
  }
  __shared__ float ls[256], lq[256];
  ls[t] = cs; lq[t] = cq;
  __syncthreads();
  int gb = t & ~3;
  float s4 = ls[gb] + ls[gb + 1] + ls[gb + 2] + ls[gb + 3];
  float q4 = lq[gb] + lq[gb + 1] + lq[gb + 2] + lq[gb + 3];
  const float cntf = 4.0f * (float)Vn;
  float mean = s4 / cntf;
  float var = q4 / cntf - mean * mean;
  float rstd = rsqrtf(var + 1e-5f);
  float scale = mod[b * 64 + c], shift = mod[b * 64 + 32 + c];
  A[t] = rstd * g[c] * scale;
  Bc[t] = (bgn[c] - mean * rstd * g[c]) * scale + shift;
}

// ------- AdaGN stage 2 + SE from conv partials -> gather affine S,T ---------------
__global__ void k_coef2(const float* __restrict__ pstat, const float* __restrict__ mod,
                        const float* __restrict__ g, const float* __restrict__ bgn,
                        const float* __restrict__ sw1, const float* __restrict__ sw2,
                        float* __restrict__ S, float* __restrict__ T) {
  __shared__ float zm[8][32];
  __shared__ float hh[8][4];
  __shared__ float ls[256], lq[256];
  int t = threadIdx.x;  // 256 = B*C
  int b = t >> 5, c = t & 31;
  float cs = 0.f, cq = 0.f;
  const float* p = pstat + (size_t)b * 32 * 64;
  for (int i = 0; i < 32; ++i) {
    cs += p[i * 64 + c];
    cq += p[i * 64 + 32 + c];
  }
  ls[t] = cs; lq[t] = cq;
  __syncthreads();
  int gb = t & ~3;
  float s4 = ls[gb] + ls[gb + 1] + ls[gb + 2] + ls[gb + 3];
  float q4 = lq[gb] + lq[gb + 1] + lq[gb + 2] + lq[gb + 3];
  const float cntf = 4.0f * (float)Vn;
  float mean = s4 / cntf;
  float var = q4 / cntf - mean * mean;
  float rstd = rsqrtf(var + 1e-5f);
  float scale = mod[b * 64 + c], shift = mod[b * 64 + 32 + c];
  float A = rstd * g[c] * scale;
  float Bv = (bgn[c] - mean * rstd * g[c]) * scale + shift;
  float chmean = cs / (float)Vn;
  zm[b][c] = A * chmean + Bv;
  __syncthreads();
  if (t < 32) {
    int b2 = t >> 2, j = t & 3;
    float hsum = 0;
    for (int cc = 0; cc < 32; ++cc) hsum += sw1[j * 32 + cc] * zm[b2][cc];
    hh[b2][j] = fmaxf(hsum, 0.f);
  }
  __syncthreads();
  float sig = 0;
  for (int j = 0; j < 4; ++j) sig += sw2[c * 4 + j] * hh[b][j];
  sig = 1.0f / (1.0f + __expf(-sig));
  S[t] = A * sig;
  T[t] = Bv * sig;
}

// ---------------- point-branch affine coefficients ----------------
__global__ void k_coefp(const float* __restrict__ psum, const float* __restrict__ psq,
                        const float* __restrict__ mod, const float* __restrict__ g,
                        const float* __restrict__ bgn, float* __restrict__ A,
                        float* __restrict__ Bc) {
  __shared__ float ls[256], lq[256];
  int t = threadIdx.x;  // 256 = B*C
  int b = t >> 5, c = t & 31;
  ls[t] = psum[t]; lq[t] = psq[t];
  __syncthreads();
  int gb = t & ~3;
  float s4 = ls[gb] + ls[gb + 1] + ls[gb + 2] + ls[gb + 3];
  float q4 = lq[gb] + lq[gb + 1] + lq[gb + 2] + lq[gb + 3];
  const float cntf = 4.0f * (float)Nn;
  float m = s4 / cntf;
  float var = q4 / cntf - m * m;
  float r = rsqrtf(var + 1e-5f);
  float scale = mod[b * 64 + c], shift = mod[b * 64 + 32 + c];
  A[t] = r * g[c] * scale;
  Bc[t] = (bgn[c] - m * r * g[c]) * scale + shift;
}

// ------- fused: trilinear devox (affine S,T) + silu(px*Ap+Bp) point branch --------
__global__ void k_devoxfinal(const u16* __restrict__ vox, const float* __restrict__ nc,
                             const u16* __restrict__ pxb, const float* __restrict__ S,
                             const float* __restrict__ T, const float* __restrict__ Ap,
                             const float* __restrict__ Bp, float* __restrict__ out) {
  int i = blockIdx.x * 256 + threadIdx.x;  // B*N
  int b = i >> 14, n = i & (Nn - 1);
  const float* ncb = nc + (size_t)b * 3 * Nn;
  float fx = ncb[n], fy = ncb[Nn + n], fz = ncb[2 * Nn + n];
  float lxf = floorf(fx), lyf = floorf(fy), lzf = floorf(fz);
  float wx1 = fx - lxf, wy1 = fy - lyf, wz1 = fz - lzf;
  int lx = (int)lxf, ly = (int)lyf, lz = (int)lzf;
  int hx = min(lx + 1, 31), hy = min(ly + 1, 31), hz = min(lz + 1, 31);
  float a[32];
  #pragma unroll
  for (int c = 0; c < 32; ++c) a[c] = 0.f;
  for (int corner = 0; corner < 8; ++corner) {
    int cx = (corner & 4) ? hx : lx;
    int cy = (corner & 2) ? hy : ly;
    int cz = (corner & 1) ? hz : lz;
    float ww = ((corner & 4) ? wx1 : 1.f - wx1) *
               ((corner & 2) ? wy1 : 1.f - wy1) *
               ((corner & 1) ? wz1 : 1.f - wz1);
    const uint4* p = reinterpret_cast<const uint4*>(
        vox + ((size_t)b * Vn + (size_t)((cx * 32 + cy) * 32 + cz)) * 32);
    #pragma unroll
    for (int qq = 0; qq < 4; ++qq) {
      float f[8];
      unpack8(p[qq], f);
      #pragma unroll
      for (int j = 0; j < 8; ++j) a[qq * 8 + j] += ww * f[j];
    }
  }
  const uint4* pp = reinterpret_cast<const uint4*>(pxb) + (size_t)i * 4;
  float* o = out + (size_t)b * 32 * Nn + n;
  #pragma unroll
  for (int qq = 0; qq < 4; ++qq) {
    float pf[8];
    unpack8(pp[qq], pf);
    #pragma unroll
    for (int j = 0; j < 8; ++j) {
      int c = qq * 8 + j;
      float y = pf[j] * Ap[b * 32 + c] + Bp[b * 32 + c];
      o[(size_t)c * Nn] = a[c] * S[b * 32 + c] + T[b * 32 + c] + siluf(y);
    }
  }
}

}  // namespace

extern "C" void kernel_launch(void* const* d_in, const int* in_sizes, int n_in,
                              void* d_out, int out_size, void* d_ws, size_t ws_size,
                              hipStream_t stream) {
  (void)in_sizes; (void)n_in; (void)out_size; (void)ws_size;
  const float* features = (const float*)d_in[0];
  const float* coords = (const float*)d_in[1];
  const float* condition = (const float*)d_in[2];
  const float* conv1_w = (const float*)d_in[3];
  const float* conv1_b = (const float*)d_in[4];
  const float* gn1_g = (const float*)d_in[5];
  const float* gn1_b = (const float*)d_in[6];
  const float* mod1_w = (const float*)d_in[7];
  const float* mod1_b = (const float*)d_in[8];
  const float* conv2_w = (const float*)d_in[9];
  const float* conv2_b = (const float*)d_in[10];
  const float* gn2_g = (const float*)d_in[11];
  const float* gn2_b = (const float*)d_in[12];
  const float* mod2_w = (const float*)d_in[13];
  const float* mod2_b = (const float*)d_in[14];
  const float* se_w1 = (const float*)d_in[15];
  const float* se_w2 = (const float*)d_in[16];
  const float* pc_w = (const float*)d_in[17];
  const float* pc_b = (const float*)d_in[18];
  const float* gnp_g = (const float*)d_in[19];
  const float* gnp_b = (const float*)d_in[20];
  const float* modp_w = (const float*)d_in[21];
  const float* modp_b = (const float*)d_in[22];

  char* w = (char*)d_ws;
  // R0a (16.8 MB): featT f32 (pxlin -> voxavg), then vox1 bf16 (conv1 -> conv2)
  float* featT = (float*)w;
  u16* vox1 = (u16*)w;
  w += 16777216;
  u16* vox2 = (u16*)w; w += 16777216;   // conv2 out -> devoxfinal
  u16* vox0 = (u16*)w; w += 16777216;   // voxavg -> conv1
  u16* pxb = (u16*)w;  w += 8388608;    // point-branch bf16 CL (pxlin -> devoxfinal)
  int* hist = (int*)w;  w += 1048576;   // memset block: hist, psump, psqp, csum, cmax
  float* psump = (float*)w; w += 1024;
  float* psqp = (float*)w;  w += 1024;
  float* csum = (float*)w;  w += 128;
  int* cmax = (int*)w;      w += 64;
  int* offs = (int*)w;  w += 1048576;
  int* bsum = (int*)w;  w += 1024;
  int* bbase = (int*)w; w += 1024;
  int* pidx = (int*)w;  w += 524288;
  float* ncb = (float*)w;   w += 1572864;
  int* vidx = (int*)w;      w += 524288;
  u16* wt1b = (u16*)w;      w += 55296;
  u16* wt2b = (u16*)w;      w += 55296;
  float* pstat1 = (float*)w; w += 65536;
  float* pstat2 = (float*)w; w += 65536;
  float* m1 = (float*)w;    w += 2048;
  float* m2 = (float*)w;    w += 2048;
  float* mp = (float*)w;    w += 2048;
  float* A1 = (float*)w;    w += 1024;
  float* B1 = (float*)w;    w += 1024;
  float* Sc = (float*)w;    w += 1024;
  float* Tc = (float*)w;    w += 1024;
  float* Ap = (float*)w;    w += 1024;
  float* Bp = (float*)w;    w += 1024;
  float* out = (float*)d_out;

  hipMemsetAsync(hist, 0, 1048576 + 1024 + 1024 + 128 + 64, stream);

  k_pxlin<<<Bn * 64, 256, 0, stream>>>(features, pc_w, pc_b, featT, pxb);
  k_cpart1<<<Bn * 8, 256, 0, stream>>>(coords, csum);
  k_twz<<<108, 256, 0, stream>>>(conv1_w, wt1b);
  k_twz<<<108, 256, 0, stream>>>(conv2_w, wt2b);
  k_mods<<<24, 256, 0, stream>>>(condition, mod1_w, mod1_b, mod2_w, mod2_b,
                                 modp_w, modp_b, m1, m2, mp);
  k_statspx<<<Bn * 16, 256, 0, stream>>>(pxb, psump, psqp, 16);
  k_coefp<<<1, 256, 0, stream>>>(psump, psqp, mp, gnp_g, gnp_b, Ap, Bp);
  k_cpart2<<<Bn * 8, 256, 0, stream>>>(coords, csum, cmax);
  k_cfinal<<<(Bn * Nn) / 256, 256, 0, stream>>>(coords, csum, cmax, ncb, vidx, hist);
  k_scan1<<<256, 256, 0, stream>>>(hist, offs, bsum);
  k_scan2<<<1, 256, 0, stream>>>(bsum, bbase);
  k_sortidx<<<(Bn * Nn) / 256, 256, 0, stream>>>(vidx, offs, bbase, pidx);
  k_voxavg<<<(Bn * Vn) / 4, 256, 0, stream>>>(hist, offs, bbase, pidx, featT,
                                              (uint2*)vox0);
  k_conv<false><<<256, 512, 0, stream>>>(vox0, wt1b, conv1_b, nullptr, nullptr,
                                         vox1, pstat1);
  k_coef1<<<1, 256, 0, stream>>>(pstat1, m1, gn1_g, gn1_b, A1, B1);
  k_conv<true><<<256, 512, 0, stream>>>(vox1, wt2b, conv2_b, A1, B1, vox2, pstat2);
  k_coef2<<<1, 256, 0, stream>>>(pstat2, m2, gn2_g, gn2_b, se_w1, se_w2, Sc, Tc);
  k_devoxfinal<<<(Bn * Nn) / 256, 256, 0, stream>>>(vox2, ncb, pxb, Sc, Tc, Ap, Bp, out);
}